// Round 1
// baseline (702.762 us; speedup 1.0000x reference)
//
#include <hip/hip_runtime.h>

typedef unsigned short u16;
typedef __attribute__((ext_vector_type(8))) __bf16 bf16x8;
typedef __attribute__((ext_vector_type(4))) float floatx4;

#define B_DIM  16
#define S_DIM  2048
#define E_DIM  768
#define HEADS  8
#define DHEAD  96
#define DHP    104      // padded LDS row (104*2B=208B, 16B aligned, 52-word stride -> only 2-way bank alias)
#define MROWS  32768    // B_DIM * S_DIM
#define QKV_LD 2304     // 3*E_DIM

__device__ __forceinline__ u16 f2b(float f) {
    unsigned u = __float_as_uint(f);
    u += 0x7fffu + ((u >> 16) & 1u);   // RNE
    return (u16)(u >> 16);
}
__device__ __forceinline__ float b2f(u16 b) {
    return __uint_as_float(((unsigned)b) << 16);
}

// ---------------- fp32 -> bf16 conversion (vectorized x4) ----------------
__global__ __launch_bounds__(256) void cvt_bf16(const float* __restrict__ in,
                                                u16* __restrict__ out, int n4) {
    int i = blockIdx.x * 256 + threadIdx.x;
    if (i < n4) {
        float4 f = ((const float4*)in)[i];
        ushort4 r;
        r.x = f2b(f.x); r.y = f2b(f.y); r.z = f2b(f.z); r.w = f2b(f.w);
        ((ushort4*)out)[i] = r;
    }
}

// ---------------- bf16 MFMA GEMM: C[m,n] = sum_k A[m,k]*W[n,k] + bias[n] ----------------
// A: M x K (row stride lda, bf16), W: N x K (dense, bf16), C: row stride ldc.
// 128x128 block tile, BK=32, 256 threads = 4 waves in 2x2, each wave 4x4 of 16x16x32 MFMA.
template<bool RELU, bool OUTF32>
__global__ __launch_bounds__(256) void gemm_bt(const u16* __restrict__ A, int lda,
                                               const u16* __restrict__ W,
                                               const float* __restrict__ bias,
                                               void* __restrict__ Cout, int ldc,
                                               int N, int K) {
    __shared__ __align__(16) u16 sA[128 * 32];
    __shared__ __align__(16) u16 sB[128 * 32];
    const int tid  = threadIdx.x;
    const int bn   = blockIdx.x;
    const int bm   = blockIdx.y;
    const int lane = tid & 63;
    const int wid  = tid >> 6;
    const int wm   = (wid >> 1) * 64;
    const int wn   = (wid & 1) * 64;
    // staging: thread t loads 16B at row t/4, col (t%4)*8; second issue covers rows +64
    const int ar = tid >> 2;
    const int ac = (tid & 3) * 8;
    const u16* Ap = A + (long)(bm * 128 + ar) * lda + ac;
    const u16* Wp = W + (long)(bn * 128 + ar) * K + ac;
    const long a2 = (long)64 * lda;
    const long w2 = (long)64 * K;

    floatx4 acc[4][4] = {};
    const int fr = lane & 15;
    const int fq = (lane >> 4) * 8;

    for (int k0 = 0; k0 < K; k0 += 32) {
        __builtin_amdgcn_global_load_lds((const __attribute__((address_space(1))) void*)(Ap + k0),
                                         (__attribute__((address_space(3))) void*)(sA + tid * 8), 16, 0, 0);
        __builtin_amdgcn_global_load_lds((const __attribute__((address_space(1))) void*)(Ap + a2 + k0),
                                         (__attribute__((address_space(3))) void*)(sA + 2048 + tid * 8), 16, 0, 0);
        __builtin_amdgcn_global_load_lds((const __attribute__((address_space(1))) void*)(Wp + k0),
                                         (__attribute__((address_space(3))) void*)(sB + tid * 8), 16, 0, 0);
        __builtin_amdgcn_global_load_lds((const __attribute__((address_space(1))) void*)(Wp + w2 + k0),
                                         (__attribute__((address_space(3))) void*)(sB + 2048 + tid * 8), 16, 0, 0);
        __syncthreads();   // compiler emits s_waitcnt vmcnt(0) before s_barrier

        bf16x8 aF[4], bF[4];
#pragma unroll
        for (int i = 0; i < 4; i++) {
            aF[i] = *(const bf16x8*)(sA + (wm + i * 16 + fr) * 32 + fq);
            bF[i] = *(const bf16x8*)(sB + (wn + i * 16 + fr) * 32 + fq);
        }
#pragma unroll
        for (int i = 0; i < 4; i++)
#pragma unroll
            for (int j = 0; j < 4; j++)
                acc[i][j] = __builtin_amdgcn_mfma_f32_16x16x32_bf16(aF[i], bF[j], acc[i][j], 0, 0, 0);
        __syncthreads();
    }

    // epilogue: C/D layout col=lane&15, row=(lane>>4)*4+r  [verified m89/m91]
    const int rq = (lane >> 4) * 4;
#pragma unroll
    for (int i = 0; i < 4; i++) {
#pragma unroll
        for (int j = 0; j < 4; j++) {
            const int row0 = bm * 128 + wm + i * 16 + rq;
            const int col  = bn * 128 + wn + j * 16 + fr;
            const float bv = bias[col];
#pragma unroll
            for (int r = 0; r < 4; r++) {
                float v = acc[i][j][r] + bv;
                if (RELU) v = fmaxf(v, 0.0f);
                if (OUTF32) ((float*)Cout)[(long)(row0 + r) * ldc + col] = v;
                else        ((u16*)Cout)[(long)(row0 + r) * ldc + col]   = f2b(v);
            }
        }
    }
}

// ---------------- attention over axis-0 (length 16) per (s,h); writes ctx in place over q-columns ----------------
__global__ __launch_bounds__(256) void attn_kernel(u16* __restrict__ qkv) {
    __shared__ __align__(16) u16 sq[16 * DHP], sk[16 * DHP], sv[16 * DHP];
    __shared__ float sS[16 * 16];
    const int tid = threadIdx.x;
    const int s = blockIdx.x >> 3;
    const int h = blockIdx.x & 7;
    // load q,k,v tiles: 3 tensors * 16 rows * 12 x (8 bf16 = 16B)
    for (int i = tid; i < 3 * 16 * 12; i += 256) {
        const int t   = i / 192;
        const int idx = i % 192;
        const int row = idx / 12;
        const int vv  = idx % 12;
        const u16* src = qkv + ((long)row * S_DIM + s) * QKV_LD + t * E_DIM + h * DHEAD + vv * 8;
        u16* dst = (t == 0 ? sq : t == 1 ? sk : sv) + row * DHP + vv * 8;
        *(uint4*)dst = *(const uint4*)src;
    }
    __syncthreads();
    // scores: thread = l*16+m
    const int l = tid >> 4, m = tid & 15;
    float sc = 0.f;
#pragma unroll 8
    for (int d = 0; d < DHEAD; d++)
        sc += b2f(sq[l * DHP + d]) * b2f(sk[m * DHP + d]);
    sc *= 0.10206207261596577f;   // 1/sqrt(96)
    // softmax over m within 16-lane groups
    float mx = sc;
#pragma unroll
    for (int off = 8; off > 0; off >>= 1) mx = fmaxf(mx, __shfl_xor(mx, off));
    float p = expf(sc - mx);
    float sum = p;
#pragma unroll
    for (int off = 8; off > 0; off >>= 1) sum += __shfl_xor(sum, off);
    sS[l * 16 + m] = p / sum;
    __syncthreads();
    // ctx[l,d] = sum_m attn[l,m] * v[m,d]; overwrite q slot (only this block ever reads it)
    for (int i = tid; i < 16 * DHEAD; i += 256) {
        const int ll = i / DHEAD, d = i % DHEAD;
        float a = 0.f;
#pragma unroll
        for (int mm = 0; mm < 16; mm++)
            a += sS[ll * 16 + mm] * b2f(sv[mm * DHP + d]);
        qkv[((long)ll * S_DIM + s) * QKV_LD + h * DHEAD + d] = f2b(a);
    }
}

// ---------------- MLP2 (dot with w2) + broadcast row over S ----------------
__global__ __launch_bounds__(256) void mlp2_bcast(const float* __restrict__ h, int ldh,
                                                  const float* __restrict__ w2,
                                                  const float* __restrict__ b2,
                                                  float* __restrict__ out) {
    __shared__ float red[4];
    const int tid = threadIdx.x;
    const long row = blockIdx.x;           // b*2048 + i
    const float* hr = h + row * ldh;
    float part = hr[tid] * w2[tid];
    if (tid < 128) part += hr[tid + 256] * w2[tid + 256];
#pragma unroll
    for (int off = 32; off > 0; off >>= 1) part += __shfl_xor(part, off);
    if ((tid & 63) == 0) red[tid >> 6] = part;
    __syncthreads();
    const float pv = red[0] + red[1] + red[2] + red[3] + b2[0];
    float4 v4 = make_float4(pv, pv, pv, pv);
    float4* dst = (float4*)(out + row * (long)S_DIM);
    dst[tid] = v4;
    dst[tid + 256] = v4;
}

extern "C" void kernel_launch(void* const* d_in, const int* in_sizes, int n_in,
                              void* d_out, int out_size, void* d_ws, size_t ws_size,
                              hipStream_t stream) {
    const float* features   = (const float*)d_in[0];
    const float* in_proj_w  = (const float*)d_in[1];
    const float* in_proj_b  = (const float*)d_in[2];
    const float* out_proj_w = (const float*)d_in[3];
    const float* out_proj_b = (const float*)d_in[4];
    const float* w1 = (const float*)d_in[5];
    const float* b1 = (const float*)d_in[6];
    const float* w2 = (const float*)d_in[7];
    const float* b2 = (const float*)d_in[8];
    float* out = (float*)d_out;

    char* p = (char*)d_ws;
    u16* fbf = (u16*)p; p += (size_t)MROWS * E_DIM * 2;        // features bf16   50.3 MB
    u16* wib = (u16*)p; p += (size_t)QKV_LD * E_DIM * 2;       // in_proj_w bf16   3.5 MB
    u16* wob = (u16*)p; p += (size_t)E_DIM * E_DIM * 2;        // out_proj_w bf16  1.2 MB
    u16* w1b = (u16*)p; p += (size_t)384 * E_DIM * 2;          // w1 bf16          0.6 MB
    u16* qkv = (u16*)p; p += (size_t)MROWS * QKV_LD * 2;       // qkv bf16         151 MB
    // in-place reuse of the qkv buffer (columns, all row stride QKV_LD=2304 u16 = 4608B):
    //   ctx      = cols [0,768)      (attention overwrites q)
    //   attn_out = cols [768,1536)
    //   h (fp32) = cols [1536,2304)  (768 u16 = 384 floats per row, ld = 1152 floats)
    u16*   ctx      = qkv;
    u16*   attn_out = qkv + E_DIM;
    float* hbuf     = (float*)(qkv + 2 * E_DIM);

    cvt_bf16<<<(MROWS * E_DIM / 4 + 255) / 256, 256, 0, stream>>>(features, fbf, MROWS * E_DIM / 4);
    cvt_bf16<<<(QKV_LD * E_DIM / 4 + 255) / 256, 256, 0, stream>>>(in_proj_w, wib, QKV_LD * E_DIM / 4);
    cvt_bf16<<<(E_DIM * E_DIM / 4 + 255) / 256, 256, 0, stream>>>(out_proj_w, wob, E_DIM * E_DIM / 4);
    cvt_bf16<<<(384 * E_DIM / 4 + 255) / 256, 256, 0, stream>>>(w1, w1b, 384 * E_DIM / 4);

    // qkv = features @ in_proj_w^T + b
    gemm_bt<false, false><<<dim3(QKV_LD / 128, MROWS / 128), 256, 0, stream>>>(
        fbf, E_DIM, wib, in_proj_b, qkv, QKV_LD, QKV_LD, E_DIM);
    // attention (writes ctx into q-columns of qkv)
    attn_kernel<<<S_DIM * HEADS, 256, 0, stream>>>(qkv);
    // attn_out = ctx @ out_proj_w^T + b
    gemm_bt<false, false><<<dim3(E_DIM / 128, MROWS / 128), 256, 0, stream>>>(
        ctx, QKV_LD, wob, out_proj_b, attn_out, QKV_LD, E_DIM, E_DIM);
    // h = relu(attn_out @ w1^T + b1), fp32 out for final-dot accuracy
    gemm_bt<true, true><<<dim3(384 / 128, MROWS / 128), 256, 0, stream>>>(
        attn_out, QKV_LD, w1b, b1, hbuf, 1152, 384, E_DIM);
    // prob + broadcast
    mlp2_bcast<<<MROWS, 256, 0, stream>>>(hbuf, 1152, w2, b2, out);
}

// Round 2
// 698.057 us; speedup vs baseline: 1.0067x; 1.0067x over previous
//
#include <hip/hip_runtime.h>

typedef unsigned short u16;
typedef __attribute__((ext_vector_type(8))) __bf16 bf16x8;
typedef __attribute__((ext_vector_type(4))) float floatx4;

#define B_DIM  16
#define S_DIM  2048
#define E_DIM  768
#define HEADS  8
#define DHEAD  96
#define MROWS  32768    // B_DIM * S_DIM
#define QKV_LD 2304     // 3*E_DIM
#define ATT_ST 392      // attn LDS row stride in u16: 384 data + 8 pad (bank offset 4/row -> free 2-way)

__device__ __forceinline__ u16 f2b(float f) {
    unsigned u = __float_as_uint(f);
    u += 0x7fffu + ((u >> 16) & 1u);   // RNE
    return (u16)(u >> 16);
}
__device__ __forceinline__ float blo(unsigned u) { return __uint_as_float(u << 16); }
__device__ __forceinline__ float bhi(unsigned u) { return __uint_as_float(u & 0xffff0000u); }

__device__ __forceinline__ void dot8(float& s, uint4 a, uint4 b) {
    s += blo(a.x) * blo(b.x) + bhi(a.x) * bhi(b.x);
    s += blo(a.y) * blo(b.y) + bhi(a.y) * bhi(b.y);
    s += blo(a.z) * blo(b.z) + bhi(a.z) * bhi(b.z);
    s += blo(a.w) * blo(b.w) + bhi(a.w) * bhi(b.w);
}
__device__ __forceinline__ void axpy8(float* acc, float p, uint4 v) {
    acc[0] += p * blo(v.x); acc[1] += p * bhi(v.x);
    acc[2] += p * blo(v.y); acc[3] += p * bhi(v.y);
    acc[4] += p * blo(v.z); acc[5] += p * bhi(v.z);
    acc[6] += p * blo(v.w); acc[7] += p * bhi(v.w);
}

// ---------------- fp32 -> bf16 conversion (vectorized x4) ----------------
__global__ __launch_bounds__(256) void cvt_bf16(const float* __restrict__ in,
                                                u16* __restrict__ out, int n4) {
    int i = blockIdx.x * 256 + threadIdx.x;
    if (i < n4) {
        float4 f = ((const float4*)in)[i];
        ushort4 r;
        r.x = f2b(f.x); r.y = f2b(f.y); r.z = f2b(f.z); r.w = f2b(f.w);
        ((ushort4*)out)[i] = r;
    }
}

// ---------------- bf16 MFMA GEMM: C[m,n] = sum_k A[m,k]*W[n,k] + bias[n] ----------------
// PERM: store logical row m at physical row (m&2047)*16 + (m>>11)  (s-major for attention)
template<bool RELU, bool OUTF32, bool PERM>
__global__ __launch_bounds__(256) void gemm_bt(const u16* __restrict__ A, int lda,
                                               const u16* __restrict__ W,
                                               const float* __restrict__ bias,
                                               void* __restrict__ Cout, int ldc,
                                               int N, int K) {
    __shared__ __align__(16) u16 sA[128 * 32];
    __shared__ __align__(16) u16 sB[128 * 32];
    const int tid  = threadIdx.x;
    const int bn   = blockIdx.x;
    const int bm   = blockIdx.y;
    const int lane = tid & 63;
    const int wid  = tid >> 6;
    const int wm   = (wid >> 1) * 64;
    const int wn   = (wid & 1) * 64;
    const int ar = tid >> 2;
    const int ac = (tid & 3) * 8;
    const u16* Ap = A + (long)(bm * 128 + ar) * lda + ac;
    const u16* Wp = W + (long)(bn * 128 + ar) * K + ac;
    const long a2 = (long)64 * lda;
    const long w2 = (long)64 * K;

    floatx4 acc[4][4] = {};
    const int fr = lane & 15;
    const int fq = (lane >> 4) * 8;

    for (int k0 = 0; k0 < K; k0 += 32) {
        __builtin_amdgcn_global_load_lds((const __attribute__((address_space(1))) void*)(Ap + k0),
                                         (__attribute__((address_space(3))) void*)(sA + tid * 8), 16, 0, 0);
        __builtin_amdgcn_global_load_lds((const __attribute__((address_space(1))) void*)(Ap + a2 + k0),
                                         (__attribute__((address_space(3))) void*)(sA + 2048 + tid * 8), 16, 0, 0);
        __builtin_amdgcn_global_load_lds((const __attribute__((address_space(1))) void*)(Wp + k0),
                                         (__attribute__((address_space(3))) void*)(sB + tid * 8), 16, 0, 0);
        __builtin_amdgcn_global_load_lds((const __attribute__((address_space(1))) void*)(Wp + w2 + k0),
                                         (__attribute__((address_space(3))) void*)(sB + 2048 + tid * 8), 16, 0, 0);
        __syncthreads();

        bf16x8 aF[4], bF[4];
#pragma unroll
        for (int i = 0; i < 4; i++) {
            aF[i] = *(const bf16x8*)(sA + (wm + i * 16 + fr) * 32 + fq);
            bF[i] = *(const bf16x8*)(sB + (wn + i * 16 + fr) * 32 + fq);
        }
#pragma unroll
        for (int i = 0; i < 4; i++)
#pragma unroll
            for (int j = 0; j < 4; j++)
                acc[i][j] = __builtin_amdgcn_mfma_f32_16x16x32_bf16(aF[i], bF[j], acc[i][j], 0, 0, 0);
        __syncthreads();
    }

    // epilogue: C/D layout col=lane&15, row=(lane>>4)*4+r  [verified m89/m91]
    const int rq = (lane >> 4) * 4;
#pragma unroll
    for (int i = 0; i < 4; i++) {
#pragma unroll
        for (int j = 0; j < 4; j++) {
            const int row0 = bm * 128 + wm + i * 16 + rq;
            const int col  = bn * 128 + wn + j * 16 + fr;
            const float bv = bias[col];
#pragma unroll
            for (int r = 0; r < 4; r++) {
                float v = acc[i][j][r] + bv;
                if (RELU) v = fmaxf(v, 0.0f);
                const int rl = row0 + r;
                const long grow = PERM ? (long)(((rl & 2047) << 4) | (rl >> 11)) : (long)rl;
                if (OUTF32) ((float*)Cout)[grow * ldc + col] = v;
                else        ((u16*)Cout)[grow * ldc + col]   = f2b(v);
            }
        }
    }
}

// ---------------- attention: block = (s, head-half); qkv rows are s-major (row' = s*16 + l) ----------------
// Loads q,k,v cols [hh*384, hh*384+384) of rows s*16..s*16+15 into LDS (coalesced 768B segments),
// computes 4 heads of 16x16 softmax-attention, writes ctx in place over its own q columns.
__global__ __launch_bounds__(256) void attn_kernel(u16* __restrict__ qkv) {
    __shared__ __align__(16) u16 sQ[16 * ATT_ST], sK[16 * ATT_ST], sV[16 * ATT_ST];
    __shared__ float sS[4][16][16];
    const int tid = threadIdx.x;
    const int s  = blockIdx.x >> 1;
    const int hh = blockIdx.x & 1;
    const u16* base = qkv + (long)s * 16 * QKV_LD + hh * 384;

    // 3 tensors * 16 rows * 48 x 16B = 2304 chunks, 9 per thread; t,l wave-uniform (boundaries at x64)
#pragma unroll
    for (int it = 0; it < 9; it++) {
        const int i = it * 256 + tid;
        const int t = i / 768, rem = i % 768, l = rem / 48, c = rem % 48;
        const u16* src = base + (long)l * QKV_LD + t * E_DIM + c * 8;
        u16* dst = (t == 0 ? sQ : t == 1 ? sK : sV) + l * ATT_ST + c * 8;
        *(uint4*)dst = *(const uint4*)src;
    }
    __syncthreads();

    const int l = tid >> 4, m = tid & 15;
#pragma unroll
    for (int h = 0; h < 4; h++) {
        float sc = 0.f;
#pragma unroll
        for (int d8 = 0; d8 < 12; d8++) {
            uint4 qw = *(const uint4*)(sQ + l * ATT_ST + h * DHEAD + d8 * 8);
            uint4 kw = *(const uint4*)(sK + m * ATT_ST + h * DHEAD + d8 * 8);
            dot8(sc, qw, kw);
        }
        sc *= 0.10206207261596577f;   // 1/sqrt(96)
        float mx = sc;
#pragma unroll
        for (int off = 8; off > 0; off >>= 1) mx = fmaxf(mx, __shfl_xor(mx, off));
        float p = __expf(sc - mx);
        float sum = p;
#pragma unroll
        for (int off = 8; off > 0; off >>= 1) sum += __shfl_xor(sum, off);
        sS[h][l][m] = p / sum;
    }
    __syncthreads();

    // ctx: 4 heads * 16 rows * 12 d8-chunks = 768 tasks; h-switches land on wave boundaries
#pragma unroll
    for (int j = 0; j < 3; j++) {
        const int task = j * 256 + tid;
        const int h = task / 192, rem = task % 192, ll = rem / 12, c = rem % 12;
        float acc[8] = {};
#pragma unroll
        for (int mm = 0; mm < 16; mm++) {
            const float p = sS[h][ll][mm];
            uint4 vw = *(const uint4*)(sV + mm * ATT_ST + h * DHEAD + c * 8);
            axpy8(acc, p, vw);
        }
        ushort4 o0, o1;
        o0.x = f2b(acc[0]); o0.y = f2b(acc[1]); o0.z = f2b(acc[2]); o0.w = f2b(acc[3]);
        o1.x = f2b(acc[4]); o1.y = f2b(acc[5]); o1.z = f2b(acc[6]); o1.w = f2b(acc[7]);
        u16* dst = qkv + ((long)s * 16 + ll) * QKV_LD + (hh * 4 + h) * DHEAD + c * 8;
        *(ushort4*)dst = o0;
        *(ushort4*)(dst + 4) = o1;
    }
}

// ---------------- MLP2 (dot with w2) + broadcast row over S; rows arrive s-major ----------------
__global__ __launch_bounds__(256) void mlp2_bcast(const float* __restrict__ h, int ldh,
                                                  const float* __restrict__ w2,
                                                  const float* __restrict__ b2,
                                                  float* __restrict__ out) {
    __shared__ float red[4];
    const int tid = threadIdx.x;
    const long rowp = blockIdx.x;          // s*16 + l
    const int  l = (int)(rowp & 15);
    const int  s = (int)(rowp >> 4);
    const float* hr = h + rowp * ldh;
    float part = hr[tid] * w2[tid];
    if (tid < 128) part += hr[tid + 256] * w2[tid + 256];
#pragma unroll
    for (int off = 32; off > 0; off >>= 1) part += __shfl_xor(part, off);
    if ((tid & 63) == 0) red[tid >> 6] = part;
    __syncthreads();
    const float pv = red[0] + red[1] + red[2] + red[3] + b2[0];
    float4 v4 = make_float4(pv, pv, pv, pv);
    float4* dst = (float4*)(out + ((long)l * S_DIM + s) * S_DIM);
    dst[tid] = v4;
    dst[tid + 256] = v4;
}

extern "C" void kernel_launch(void* const* d_in, const int* in_sizes, int n_in,
                              void* d_out, int out_size, void* d_ws, size_t ws_size,
                              hipStream_t stream) {
    const float* features   = (const float*)d_in[0];
    const float* in_proj_b  = (const float*)d_in[2];
    const float* out_proj_b = (const float*)d_in[4];
    const float* b1 = (const float*)d_in[6];
    const float* w2 = (const float*)d_in[7];
    const float* b2 = (const float*)d_in[8];
    float* out = (float*)d_out;

    char* p = (char*)d_ws;
    u16* fbf = (u16*)p; p += (size_t)MROWS * E_DIM * 2;        // features bf16   50.3 MB
    u16* wib = (u16*)p; p += (size_t)QKV_LD * E_DIM * 2;       // in_proj_w bf16   3.5 MB
    u16* wob = (u16*)p; p += (size_t)E_DIM * E_DIM * 2;       // out_proj_w bf16  1.2 MB
    u16* w1b = (u16*)p; p += (size_t)384 * E_DIM * 2;          // w1 bf16          0.6 MB
    u16* qkv = (u16*)p; p += (size_t)MROWS * QKV_LD * 2;       // qkv bf16 (s-major rows)  151 MB
    // column reuse inside qkv rows (stride QKV_LD=2304 u16 = 4608B):
    //   ctx      = cols [0,768)     (attention overwrites q in place)
    //   attn_out = cols [768,1536)
    //   h (fp32) = cols [1536,2304) (= 384 floats, ld = 1152 floats)
    u16*   ctx      = qkv;
    u16*   attn_out = qkv + E_DIM;
    float* hbuf     = (float*)(qkv + 2 * E_DIM);

    cvt_bf16<<<(MROWS * E_DIM / 4 + 255) / 256, 256, 0, stream>>>(features, fbf, MROWS * E_DIM / 4);
    cvt_bf16<<<(QKV_LD * E_DIM / 4 + 255) / 256, 256, 0, stream>>>((const float*)d_in[1], wib, QKV_LD * E_DIM / 4);
    cvt_bf16<<<(E_DIM * E_DIM / 4 + 255) / 256, 256, 0, stream>>>((const float*)d_in[3], wob, E_DIM * E_DIM / 4);
    cvt_bf16<<<(384 * E_DIM / 4 + 255) / 256, 256, 0, stream>>>((const float*)d_in[5], w1b, 384 * E_DIM / 4);

    // qkv = features @ in_proj_w^T + b, stored s-major (PERM)
    gemm_bt<false, false, true><<<dim3(QKV_LD / 128, MROWS / 128), 256, 0, stream>>>(
        fbf, E_DIM, wib, in_proj_b, qkv, QKV_LD, QKV_LD, E_DIM);
    // attention (in place into q-columns)
    attn_kernel<<<S_DIM * 2, 256, 0, stream>>>(qkv);
    // attn_out = ctx @ out_proj_w^T + b   (rows stay s-major)
    gemm_bt<false, false, false><<<dim3(E_DIM / 128, MROWS / 128), 256, 0, stream>>>(
        ctx, QKV_LD, wob, out_proj_b, attn_out, QKV_LD, E_DIM, E_DIM);
    // h = relu(attn_out @ w1^T + b1), fp32
    gemm_bt<true, true, false><<<dim3(384 / 128, MROWS / 128), 256, 0, stream>>>(
        attn_out, QKV_LD, w1b, b1, hbuf, 1152, 384, E_DIM);
    // prob + broadcast (undo s-major in output addressing)
    mlp2_bcast<<<MROWS, 256, 0, stream>>>(hbuf, 1152, w2, b2, out);
}

// Round 3
// 663.800 us; speedup vs baseline: 1.0587x; 1.0516x over previous
//
#include <hip/hip_runtime.h>

typedef unsigned short u16;
typedef __attribute__((ext_vector_type(8))) __bf16 bf16x8;
typedef __attribute__((ext_vector_type(4))) float floatx4;

#define B_DIM  16
#define S_DIM  2048
#define E_DIM  768
#define HEADS  8
#define DHEAD  96
#define MROWS  32768    // B_DIM * S_DIM
#define QKV_LD 2304     // 3*E_DIM
#define ATT_ST 392      // attn LDS row stride in u16

__device__ __forceinline__ u16 f2b(float f) {
    unsigned u = __float_as_uint(f);
    u += 0x7fffu + ((u >> 16) & 1u);   // RNE
    return (u16)(u >> 16);
}
__device__ __forceinline__ float blo(unsigned u) { return __uint_as_float(u << 16); }
__device__ __forceinline__ float bhi(unsigned u) { return __uint_as_float(u & 0xffff0000u); }

__device__ __forceinline__ void axpy8(float* acc, float p, uint4 v) {
    acc[0] += p * blo(v.x); acc[1] += p * bhi(v.x);
    acc[2] += p * blo(v.y); acc[3] += p * bhi(v.y);
    acc[4] += p * blo(v.z); acc[5] += p * bhi(v.z);
    acc[6] += p * blo(v.w); acc[7] += p * bhi(v.w);
}

// ---------------- fp32 -> bf16 conversion ----------------
__global__ __launch_bounds__(256) void cvt_bf16(const float* __restrict__ in,
                                                u16* __restrict__ out, int n4) {
    int i = blockIdx.x * 256 + threadIdx.x;
    if (i < n4) {
        float4 f = ((const float4*)in)[i];
        ushort4 r;
        r.x = f2b(f.x); r.y = f2b(f.y); r.z = f2b(f.z); r.w = f2b(f.w);
        ((ushort4*)out)[i] = r;
    }
}

// ---------------- 768x768 fp32 -> bf16 transpose (for Wo^T) ----------------
__global__ __launch_bounds__(256) void transpose_cvt(const float* __restrict__ in,
                                                     u16* __restrict__ out) {
    __shared__ float t[32][33];
    const int tx = threadIdx.x & 31, ty = threadIdx.x >> 5;   // 32 x 8
    int x = blockIdx.x * 32 + tx;
    int y = blockIdx.y * 32 + ty;
#pragma unroll
    for (int j = 0; j < 4; j++) t[ty + j * 8][tx] = in[(long)(y + j * 8) * 768 + x];
    __syncthreads();
    x = blockIdx.y * 32 + tx;
    y = blockIdx.x * 32 + ty;
#pragma unroll
    for (int j = 0; j < 4; j++) out[(long)(y + j * 8) * 768 + x] = f2b(t[tx][ty + j * 8]);
}

// ---------------- c[n] = b1[n] + sum_e W1[n][e]*bo[e]  (384 x 768 dot) ----------------
__global__ __launch_bounds__(64) void cbias_kernel(const float* __restrict__ w1,
                                                   const float* __restrict__ bo,
                                                   const float* __restrict__ b1,
                                                   float* __restrict__ c) {
    const int n = blockIdx.x * 64 + threadIdx.x;
    if (n < 384) {
        float s = b1[n];
        const float* row = w1 + (long)n * 768;
        for (int e = 0; e < 768; e++) s += row[e] * bo[e];
        c[n] = s;
    }
}

// ---------------- bf16 MFMA GEMM: C[m,n] = sum_k A[m,k]*W[n,k] + bias[n] ----------------
// PERM: store logical row m at physical row (m&2047)*16 + (m>>11)  (s-major)
// SWIZ: grid is linear 4608 blocks (for N=2304,M=32768 only): XCD-aware mapping.
template<bool OUTF32, bool PERM, bool SWIZ>
__global__ __launch_bounds__(256) void gemm_bt(const u16* __restrict__ A, int lda,
                                               const u16* __restrict__ W,
                                               const float* __restrict__ bias,
                                               void* __restrict__ Cout, int ldc,
                                               int N, int K) {
    __shared__ __align__(16) u16 sA[128 * 32];
    __shared__ __align__(16) u16 sB[128 * 32];
    const int tid  = threadIdx.x;
    int bn, bm;
    if (SWIZ) {
        // bm stripe of 32 per XCD (bx&7), bn rotates slowest -> W-panel L2-resident
        const int bx = blockIdx.x;
        bn = bx >> 8;
        bm = ((bx & 7) << 5) | ((bx >> 3) & 31);
    } else {
        bn = blockIdx.x;
        bm = blockIdx.y;
    }
    const int lane = tid & 63;
    const int wid  = tid >> 6;
    const int wm   = (wid >> 1) * 64;
    const int wn   = (wid & 1) * 64;
    const int ar = tid >> 2;
    const int ac = (tid & 3) * 8;
    const u16* Ap = A + (long)(bm * 128 + ar) * lda + ac;
    const u16* Wp = W + (long)(bn * 128 + ar) * K + ac;
    const long a2 = (long)64 * lda;
    const long w2 = (long)64 * K;

    floatx4 acc[4][4] = {};
    const int fr = lane & 15;
    const int fq = (lane >> 4) * 8;

    for (int k0 = 0; k0 < K; k0 += 32) {
        __builtin_amdgcn_global_load_lds((const __attribute__((address_space(1))) void*)(Ap + k0),
                                         (__attribute__((address_space(3))) void*)(sA + tid * 8), 16, 0, 0);
        __builtin_amdgcn_global_load_lds((const __attribute__((address_space(1))) void*)(Ap + a2 + k0),
                                         (__attribute__((address_space(3))) void*)(sA + 2048 + tid * 8), 16, 0, 0);
        __builtin_amdgcn_global_load_lds((const __attribute__((address_space(1))) void*)(Wp + k0),
                                         (__attribute__((address_space(3))) void*)(sB + tid * 8), 16, 0, 0);
        __builtin_amdgcn_global_load_lds((const __attribute__((address_space(1))) void*)(Wp + w2 + k0),
                                         (__attribute__((address_space(3))) void*)(sB + 2048 + tid * 8), 16, 0, 0);
        __syncthreads();

        bf16x8 aF[4], bF[4];
#pragma unroll
        for (int i = 0; i < 4; i++) {
            aF[i] = *(const bf16x8*)(sA + (wm + i * 16 + fr) * 32 + fq);
            bF[i] = *(const bf16x8*)(sB + (wn + i * 16 + fr) * 32 + fq);
        }
#pragma unroll
        for (int i = 0; i < 4; i++)
#pragma unroll
            for (int j = 0; j < 4; j++)
                acc[i][j] = __builtin_amdgcn_mfma_f32_16x16x32_bf16(aF[i], bF[j], acc[i][j], 0, 0, 0);
        __syncthreads();
    }

    const int rq = (lane >> 4) * 4;
#pragma unroll
    for (int i = 0; i < 4; i++) {
#pragma unroll
        for (int j = 0; j < 4; j++) {
            const int row0 = bm * 128 + wm + i * 16 + rq;
            const int col  = bn * 128 + wn + j * 16 + fr;
            const float bv = bias[col];
#pragma unroll
            for (int r = 0; r < 4; r++) {
                float v = acc[i][j][r] + bv;
                const int rl = row0 + r;
                const long grow = PERM ? (long)(((rl & 2047) << 4) | (rl >> 11)) : (long)rl;
                if (OUTF32) ((float*)Cout)[grow * ldc + col] = v;
                else        ((u16*)Cout)[grow * ldc + col]   = f2b(v);
            }
        }
    }
}

// ---------------- attention: block = (s, head-half); MFMA scores + in-reg softmax ----------------
__global__ __launch_bounds__(256) void attn_kernel(u16* __restrict__ qkv) {
    __shared__ __align__(16) u16 sQ[16 * ATT_ST], sK[16 * ATT_ST], sV[16 * ATT_ST];
    __shared__ float sS[4][16][16];
    const int tid = threadIdx.x;
    const int s  = blockIdx.x >> 1;
    const int hh = blockIdx.x & 1;
    const u16* base = qkv + (long)s * 16 * QKV_LD + hh * 384;

#pragma unroll
    for (int it = 0; it < 9; it++) {
        const int i = it * 256 + tid;
        const int t = i / 768, rem = i % 768, l = rem / 48, c = rem % 48;
        const u16* src = base + (long)l * QKV_LD + t * E_DIM + c * 8;
        u16* dst = (t == 0 ? sQ : t == 1 ? sK : sV) + l * ATT_ST + c * 8;
        *(uint4*)dst = *(const uint4*)src;
    }
    __syncthreads();

    // wave w computes head w: S = Q·K^T via 3 MFMAs (K=96), softmax in C-layout regs
    const int lane = tid & 63;
    const int w    = tid >> 6;
    const int fr   = lane & 15;
    const int fq   = (lane >> 4) * 8;
    floatx4 acc = {};
    const u16* qrow = sQ + fr * ATT_ST + w * DHEAD + fq;
    const u16* krow = sK + fr * ATT_ST + w * DHEAD + fq;
#pragma unroll
    for (int st = 0; st < 3; st++) {
        bf16x8 qa = *(const bf16x8*)(qrow + st * 32);
        bf16x8 kb = *(const bf16x8*)(krow + st * 32);
        acc = __builtin_amdgcn_mfma_f32_16x16x32_bf16(qa, kb, acc, 0, 0, 0);
    }
    const int rq = (lane >> 4) * 4;
#pragma unroll
    for (int r = 0; r < 4; r++) {
        float sc = acc[r] * 0.10206207261596577f;   // 1/sqrt(96)
        float mx = sc;
#pragma unroll
        for (int off = 8; off > 0; off >>= 1) mx = fmaxf(mx, __shfl_xor(mx, off));
        float e = __expf(sc - mx);
        float sum = e;
#pragma unroll
        for (int off = 8; off > 0; off >>= 1) sum += __shfl_xor(sum, off);
        sS[w][rq + r][fr] = e / sum;   // row l = rq+r, col m = fr
    }
    __syncthreads();

    // ctx = P @ V, VALU path; write in place over q columns
#pragma unroll
    for (int j = 0; j < 3; j++) {
        const int task = j * 256 + tid;
        const int h = task / 192, rem = task % 192, ll = rem / 12, c = rem % 12;
        float a[8] = {};
#pragma unroll
        for (int mm = 0; mm < 16; mm++) {
            const float p = sS[h][ll][mm];
            uint4 vw = *(const uint4*)(sV + mm * ATT_ST + h * DHEAD + c * 8);
            axpy8(a, p, vw);
        }
        ushort4 o0, o1;
        o0.x = f2b(a[0]); o0.y = f2b(a[1]); o0.z = f2b(a[2]); o0.w = f2b(a[3]);
        o1.x = f2b(a[4]); o1.y = f2b(a[5]); o1.z = f2b(a[6]); o1.w = f2b(a[7]);
        u16* dst = qkv + ((long)s * 16 + ll) * QKV_LD + (hh * 4 + h) * DHEAD + c * 8;
        *(ushort4*)dst = o0;
        *(ushort4*)(dst + 4) = o1;
    }
}

// ---------------- fused MLP: prob = relu(ctx@G^T + c)@w2 + b2, then broadcast write ----------------
// Grid 256 blocks, each: 128 rows x full N=384 (3 n-panels), then writes 128 x 2048 output rows.
__global__ __launch_bounds__(256) void mlp_fused(const u16* __restrict__ A, int lda,
                                                 const u16* __restrict__ G,
                                                 const float* __restrict__ cbias,
                                                 const float* __restrict__ w2,
                                                 const float* __restrict__ b2,
                                                 float* __restrict__ out) {
    __shared__ __align__(16) u16 sA[128 * 32];
    __shared__ __align__(16) u16 sB[128 * 32];
    __shared__ float rowsum[128];
    const int tid = threadIdx.x;
    const int bm  = blockIdx.x;
    if (tid < 128) rowsum[tid] = 0.f;
    const int lane = tid & 63;
    const int wid  = tid >> 6;
    const int wm   = (wid >> 1) * 64;
    const int wn   = (wid & 1) * 64;
    const int ar = tid >> 2;
    const int ac = (tid & 3) * 8;
    const u16* Ap = A + (long)(bm * 128 + ar) * lda + ac;
    const long a2 = (long)64 * lda;
    const int fr = lane & 15;
    const int fq = (lane >> 4) * 8;
    const int rq = (lane >> 4) * 4;

    for (int bn = 0; bn < 3; bn++) {
        const u16* Wp = G + (long)(bn * 128 + ar) * 768 + ac;
        floatx4 acc[4][4] = {};
        for (int k0 = 0; k0 < 768; k0 += 32) {
            __builtin_amdgcn_global_load_lds((const __attribute__((address_space(1))) void*)(Ap + k0),
                                             (__attribute__((address_space(3))) void*)(sA + tid * 8), 16, 0, 0);
            __builtin_amdgcn_global_load_lds((const __attribute__((address_space(1))) void*)(Ap + a2 + k0),
                                             (__attribute__((address_space(3))) void*)(sA + 2048 + tid * 8), 16, 0, 0);
            __builtin_amdgcn_global_load_lds((const __attribute__((address_space(1))) void*)(Wp + k0),
                                             (__attribute__((address_space(3))) void*)(sB + tid * 8), 16, 0, 0);
            __builtin_amdgcn_global_load_lds((const __attribute__((address_space(1))) void*)(Wp + (long)64 * 768 + k0),
                                             (__attribute__((address_space(3))) void*)(sB + 2048 + tid * 8), 16, 0, 0);
            __syncthreads();
            bf16x8 aF[4], bF[4];
#pragma unroll
            for (int i = 0; i < 4; i++) {
                aF[i] = *(const bf16x8*)(sA + (wm + i * 16 + fr) * 32 + fq);
                bF[i] = *(const bf16x8*)(sB + (wn + i * 16 + fr) * 32 + fq);
            }
#pragma unroll
            for (int i = 0; i < 4; i++)
#pragma unroll
                for (int j = 0; j < 4; j++)
                    acc[i][j] = __builtin_amdgcn_mfma_f32_16x16x32_bf16(aF[i], bF[j], acc[i][j], 0, 0, 0);
            __syncthreads();
        }
        // epilogue: part[i][r] = sum_j relu(acc + c[col])*w2[col]; reduce over fr lanes
        float part[4][4] = {};
#pragma unroll
        for (int j = 0; j < 4; j++) {
            const int col = bn * 128 + wn + j * 16 + fr;
            const float cv = cbias[col];
            const float wv = w2[col];
#pragma unroll
            for (int i = 0; i < 4; i++)
#pragma unroll
                for (int r = 0; r < 4; r++)
                    part[i][r] += fmaxf(acc[i][j][r] + cv, 0.f) * wv;
        }
#pragma unroll
        for (int i = 0; i < 4; i++)
#pragma unroll
            for (int r = 0; r < 4; r++) {
                float v = part[i][r];
#pragma unroll
                for (int off = 8; off > 0; off >>= 1) v += __shfl_xor(v, off);
                if (fr == 0) atomicAdd(&rowsum[wm + i * 16 + rq + r], v);
            }
    }
    __syncthreads();
    const float b2v = b2[0];
    for (int rr = 0; rr < 128; rr++) {
        const float pv = rowsum[rr] + b2v;
        const int p_ = bm * 128 + rr;   // physical (s-major) row: s = p_>>4, l = p_&15
        float4* dst = (float4*)(out + ((long)(p_ & 15) * S_DIM + (p_ >> 4)) * S_DIM);
        float4 v4 = make_float4(pv, pv, pv, pv);
        dst[tid] = v4;
        dst[tid + 256] = v4;
    }
}

extern "C" void kernel_launch(void* const* d_in, const int* in_sizes, int n_in,
                              void* d_out, int out_size, void* d_ws, size_t ws_size,
                              hipStream_t stream) {
    const float* features   = (const float*)d_in[0];
    const float* in_proj_b  = (const float*)d_in[2];
    const float* out_proj_b = (const float*)d_in[4];
    const float* b1 = (const float*)d_in[6];
    const float* w2 = (const float*)d_in[7];
    const float* b2 = (const float*)d_in[8];
    float* out = (float*)d_out;

    char* p = (char*)d_ws;
    u16* fbf = (u16*)p; p += (size_t)MROWS * E_DIM * 2;        // features bf16    50.3 MB
    u16* wib = (u16*)p; p += (size_t)QKV_LD * E_DIM * 2;       // in_proj_w bf16    3.5 MB
    u16* w1b = (u16*)p; p += (size_t)384 * E_DIM * 2;          // w1 bf16           0.6 MB
    u16* WoT = (u16*)p; p += (size_t)E_DIM * E_DIM * 2;        // out_proj_w^T bf16 1.2 MB
    u16* Gbf = (u16*)p; p += (size_t)384 * E_DIM * 2;          // G = W1@Wo bf16    0.6 MB
    float* cbuf  = (float*)p; p += 384 * 4;
    float* zeros = (float*)p; p += 768 * 4;
    p = (char*)(((size_t)p + 255) & ~(size_t)255);
    u16* qkv = (u16*)p; p += (size_t)MROWS * QKV_LD * 2;       // qkv bf16 (s-major) 151 MB
    u16* ctx = qkv;                                            // attention writes over q cols

    hipMemsetAsync(zeros, 0, 768 * 4, stream);

    cvt_bf16<<<(MROWS * E_DIM / 4 + 255) / 256, 256, 0, stream>>>(features, fbf, MROWS * E_DIM / 4);
    cvt_bf16<<<(QKV_LD * E_DIM / 4 + 255) / 256, 256, 0, stream>>>((const float*)d_in[1], wib, QKV_LD * E_DIM / 4);
    cvt_bf16<<<(384 * E_DIM / 4 + 255) / 256, 256, 0, stream>>>((const float*)d_in[5], w1b, 384 * E_DIM / 4);
    transpose_cvt<<<dim3(24, 24), 256, 0, stream>>>((const float*)d_in[3], WoT);
    cbias_kernel<<<6, 64, 0, stream>>>((const float*)d_in[5], out_proj_b, b1, cbuf);

    // G = W1 @ Wo  (A=w1b 384x768, W=Wo^T 768x768, contraction over e)
    gemm_bt<false, false, false><<<dim3(6, 3), 256, 0, stream>>>(
        w1b, E_DIM, WoT, zeros, Gbf, E_DIM, E_DIM, E_DIM);
    // qkv = features @ in_proj_w^T + b, s-major, XCD-swizzled linear grid
    gemm_bt<false, true, true><<<dim3(4608), 256, 0, stream>>>(
        fbf, E_DIM, wib, in_proj_b, qkv, QKV_LD, QKV_LD, E_DIM);
    // attention (in place into q-columns)
    attn_kernel<<<S_DIM * 2, 256, 0, stream>>>(qkv);
    // fused MLP + broadcast
    mlp_fused<<<256, 256, 0, stream>>>(ctx, QKV_LD, Gbf, cbuf, w2, b2, out);
}

// Round 4
// 622.069 us; speedup vs baseline: 1.1297x; 1.0671x over previous
//
#include <hip/hip_runtime.h>

typedef unsigned short u16;
typedef __attribute__((ext_vector_type(8))) __bf16 bf16x8;
typedef __attribute__((ext_vector_type(4))) float floatx4;

#define B_DIM  16
#define S_DIM  2048
#define E_DIM  768
#define HEADS  8
#define DHEAD  96
#define MROWS  32768    // B_DIM * S_DIM
#define QKV_LD 2304     // 3*E_DIM
#define ATT_ST 392      // attn LDS row stride in u16

__device__ __forceinline__ u16 f2b(float f) {
    unsigned u = __float_as_uint(f);
    u += 0x7fffu + ((u >> 16) & 1u);   // RNE
    return (u16)(u >> 16);
}
__device__ __forceinline__ float blo(unsigned u) { return __uint_as_float(u << 16); }
__device__ __forceinline__ float bhi(unsigned u) { return __uint_as_float(u & 0xffff0000u); }

__device__ __forceinline__ void axpy8(float* acc, float p, uint4 v) {
    acc[0] += p * blo(v.x); acc[1] += p * bhi(v.x);
    acc[2] += p * blo(v.y); acc[3] += p * bhi(v.y);
    acc[4] += p * blo(v.z); acc[5] += p * bhi(v.z);
    acc[6] += p * blo(v.w); acc[7] += p * bhi(v.w);
}

// ---------------- fp32 -> bf16 conversion ----------------
__global__ __launch_bounds__(256) void cvt_bf16(const float* __restrict__ in,
                                                u16* __restrict__ out, int n4) {
    int i = blockIdx.x * 256 + threadIdx.x;
    if (i < n4) {
        float4 f = ((const float4*)in)[i];
        ushort4 r;
        r.x = f2b(f.x); r.y = f2b(f.y); r.z = f2b(f.z); r.w = f2b(f.w);
        ((ushort4*)out)[i] = r;
    }
}

// ---------------- 768x768 fp32 -> bf16 transpose (for Wo^T) ----------------
__global__ __launch_bounds__(256) void transpose_cvt(const float* __restrict__ in,
                                                     u16* __restrict__ out) {
    __shared__ float t[32][33];
    const int tx = threadIdx.x & 31, ty = threadIdx.x >> 5;   // 32 x 8
    int x = blockIdx.x * 32 + tx;
    int y = blockIdx.y * 32 + ty;
#pragma unroll
    for (int j = 0; j < 4; j++) t[ty + j * 8][tx] = in[(long)(y + j * 8) * 768 + x];
    __syncthreads();
    x = blockIdx.y * 32 + tx;
    y = blockIdx.x * 32 + ty;
#pragma unroll
    for (int j = 0; j < 4; j++) out[(long)(y + j * 8) * 768 + x] = f2b(t[tx][ty + j * 8]);
}

// ---------------- c[n] = b1[n] + sum_e W1[n][e]*bo[e]  (block per n, coalesced) ----------------
__global__ __launch_bounds__(256) void cbias_kernel(const float* __restrict__ w1,
                                                    const float* __restrict__ bo,
                                                    const float* __restrict__ b1,
                                                    float* __restrict__ c) {
    __shared__ float red[4];
    const int n = blockIdx.x, tid = threadIdx.x;
    const float* row = w1 + (long)n * 768;
    float s = row[tid] * bo[tid] + row[tid + 256] * bo[tid + 256] + row[tid + 512] * bo[tid + 512];
#pragma unroll
    for (int off = 32; off > 0; off >>= 1) s += __shfl_xor(s, off);
    if ((tid & 63) == 0) red[tid >> 6] = s;
    __syncthreads();
    if (tid == 0) c[n] = red[0] + red[1] + red[2] + red[3] + b1[n];
}

// ---------------- bf16 MFMA GEMM: C[m,n] = sum_k A[m,k]*W[n,k] + bias[n] ----------------
// PERM: store logical row m at physical row (m&2047)*16 + (m>>11)  (s-major)
// SWIZ: grid is linear 4608 blocks (for N=2304,M=32768 only): XCD-aware mapping.
template<bool OUTF32, bool PERM, bool SWIZ>
__global__ __launch_bounds__(256) void gemm_bt(const u16* __restrict__ A, int lda,
                                               const u16* __restrict__ W,
                                               const float* __restrict__ bias,
                                               void* __restrict__ Cout, int ldc,
                                               int N, int K) {
    __shared__ __align__(16) u16 sA[128 * 32];
    __shared__ __align__(16) u16 sB[128 * 32];
    const int tid  = threadIdx.x;
    int bn, bm;
    if (SWIZ) {
        const int bx = blockIdx.x;
        bn = bx >> 8;
        bm = ((bx & 7) << 5) | ((bx >> 3) & 31);
    } else {
        bn = blockIdx.x;
        bm = blockIdx.y;
    }
    const int lane = tid & 63;
    const int wid  = tid >> 6;
    const int wm   = (wid >> 1) * 64;
    const int wn   = (wid & 1) * 64;
    const int ar = tid >> 2;
    const int ac = (tid & 3) * 8;
    const u16* Ap = A + (long)(bm * 128 + ar) * lda + ac;
    const u16* Wp = W + (long)(bn * 128 + ar) * K + ac;
    const long a2 = (long)64 * lda;
    const long w2 = (long)64 * K;

    floatx4 acc[4][4] = {};
    const int fr = lane & 15;
    const int fq = (lane >> 4) * 8;

    for (int k0 = 0; k0 < K; k0 += 32) {
        __builtin_amdgcn_global_load_lds((const __attribute__((address_space(1))) void*)(Ap + k0),
                                         (__attribute__((address_space(3))) void*)(sA + tid * 8), 16, 0, 0);
        __builtin_amdgcn_global_load_lds((const __attribute__((address_space(1))) void*)(Ap + a2 + k0),
                                         (__attribute__((address_space(3))) void*)(sA + 2048 + tid * 8), 16, 0, 0);
        __builtin_amdgcn_global_load_lds((const __attribute__((address_space(1))) void*)(Wp + k0),
                                         (__attribute__((address_space(3))) void*)(sB + tid * 8), 16, 0, 0);
        __builtin_amdgcn_global_load_lds((const __attribute__((address_space(1))) void*)(Wp + w2 + k0),
                                         (__attribute__((address_space(3))) void*)(sB + 2048 + tid * 8), 16, 0, 0);
        __syncthreads();

        bf16x8 aF[4], bF[4];
#pragma unroll
        for (int i = 0; i < 4; i++) {
            aF[i] = *(const bf16x8*)(sA + (wm + i * 16 + fr) * 32 + fq);
            bF[i] = *(const bf16x8*)(sB + (wn + i * 16 + fr) * 32 + fq);
        }
#pragma unroll
        for (int i = 0; i < 4; i++)
#pragma unroll
            for (int j = 0; j < 4; j++)
                acc[i][j] = __builtin_amdgcn_mfma_f32_16x16x32_bf16(aF[i], bF[j], acc[i][j], 0, 0, 0);
        __syncthreads();
    }

    const int rq = (lane >> 4) * 4;
#pragma unroll
    for (int i = 0; i < 4; i++) {
#pragma unroll
        for (int j = 0; j < 4; j++) {
            const int row0 = bm * 128 + wm + i * 16 + rq;
            const int col  = bn * 128 + wn + j * 16 + fr;
            const float bv = bias[col];
#pragma unroll
            for (int r = 0; r < 4; r++) {
                float v = acc[i][j][r] + bv;
                const int rl = row0 + r;
                const long grow = PERM ? (long)(((rl & 2047) << 4) | (rl >> 11)) : (long)rl;
                if (OUTF32) ((float*)Cout)[grow * ldc + col] = v;
                else        ((u16*)Cout)[grow * ldc + col]   = f2b(v);
            }
        }
    }
}

// ---------------- attention: block = (s, head-half); MFMA scores + in-reg softmax ----------------
__global__ __launch_bounds__(256) void attn_kernel(u16* __restrict__ qkv) {
    __shared__ __align__(16) u16 sQ[16 * ATT_ST], sK[16 * ATT_ST], sV[16 * ATT_ST];
    __shared__ float sS[4][16][16];
    const int tid = threadIdx.x;
    const int s  = blockIdx.x >> 1;
    const int hh = blockIdx.x & 1;
    const u16* base = qkv + (long)s * 16 * QKV_LD + hh * 384;

#pragma unroll
    for (int it = 0; it < 9; it++) {
        const int i = it * 256 + tid;
        const int t = i / 768, rem = i % 768, l = rem / 48, c = rem % 48;
        const u16* src = base + (long)l * QKV_LD + t * E_DIM + c * 8;
        u16* dst = (t == 0 ? sQ : t == 1 ? sK : sV) + l * ATT_ST + c * 8;
        *(uint4*)dst = *(const uint4*)src;
    }
    __syncthreads();

    const int lane = tid & 63;
    const int w    = tid >> 6;
    const int fr   = lane & 15;
    const int fq   = (lane >> 4) * 8;
    floatx4 acc = {};
    const u16* qrow = sQ + fr * ATT_ST + w * DHEAD + fq;
    const u16* krow = sK + fr * ATT_ST + w * DHEAD + fq;
#pragma unroll
    for (int st = 0; st < 3; st++) {
        bf16x8 qa = *(const bf16x8*)(qrow + st * 32);
        bf16x8 kb = *(const bf16x8*)(krow + st * 32);
        acc = __builtin_amdgcn_mfma_f32_16x16x32_bf16(qa, kb, acc, 0, 0, 0);
    }
    const int rq = (lane >> 4) * 4;
#pragma unroll
    for (int r = 0; r < 4; r++) {
        float sc = acc[r] * 0.10206207261596577f;   // 1/sqrt(96)
        float mx = sc;
#pragma unroll
        for (int off = 8; off > 0; off >>= 1) mx = fmaxf(mx, __shfl_xor(mx, off));
        float e = __expf(sc - mx);
        float sum = e;
#pragma unroll
        for (int off = 8; off > 0; off >>= 1) sum += __shfl_xor(sum, off);
        sS[w][rq + r][fr] = e / sum;
    }
    __syncthreads();

#pragma unroll
    for (int j = 0; j < 3; j++) {
        const int task = j * 256 + tid;
        const int h = task / 192, rem = task % 192, ll = rem / 12, c = rem % 12;
        float a[8] = {};
#pragma unroll
        for (int mm = 0; mm < 16; mm++) {
            const float p = sS[h][ll][mm];
            uint4 vw = *(const uint4*)(sV + mm * ATT_ST + h * DHEAD + c * 8);
            axpy8(a, p, vw);
        }
        ushort4 o0, o1;
        o0.x = f2b(a[0]); o0.y = f2b(a[1]); o0.z = f2b(a[2]); o0.w = f2b(a[3]);
        o1.x = f2b(a[4]); o1.y = f2b(a[5]); o1.z = f2b(a[6]); o1.w = f2b(a[7]);
        u16* dst = qkv + ((long)s * 16 + ll) * QKV_LD + (hh * 4 + h) * DHEAD + c * 8;
        *(ushort4*)dst = o0;
        *(ushort4*)(dst + 4) = o1;
    }
}

// ---------------- MLP GEMM panel: part[panel][row] = sum_{n in panel} relu(ctx@G^T + c)[row,n]*w2[n] ----------------
// Grid 768 linear: bx = bm*3 + panel (panel fastest -> concurrent blocks share the A-tile).
__global__ __launch_bounds__(256) void mlp_gemm(const u16* __restrict__ A, int lda,
                                                const u16* __restrict__ G,
                                                const float* __restrict__ cbias,
                                                const float* __restrict__ w2,
                                                float* __restrict__ part) {
    __shared__ __align__(16) u16 sA[128 * 32];
    __shared__ __align__(16) u16 sB[128 * 32];
    __shared__ float rowsum[128];
    const int tid = threadIdx.x;
    const int bm  = blockIdx.x / 3;
    const int bn  = blockIdx.x % 3;
    if (tid < 128) rowsum[tid] = 0.f;
    const int lane = tid & 63;
    const int wid  = tid >> 6;
    const int wm   = (wid >> 1) * 64;
    const int wn   = (wid & 1) * 64;
    const int ar = tid >> 2;
    const int ac = (tid & 3) * 8;
    const u16* Ap = A + (long)(bm * 128 + ar) * lda + ac;
    const u16* Wp = G + (long)(bn * 128 + ar) * 768 + ac;
    const long a2 = (long)64 * lda;
    const int fr = lane & 15;
    const int fq = (lane >> 4) * 8;
    const int rq = (lane >> 4) * 4;

    floatx4 acc[4][4] = {};
    for (int k0 = 0; k0 < 768; k0 += 32) {
        __builtin_amdgcn_global_load_lds((const __attribute__((address_space(1))) void*)(Ap + k0),
                                         (__attribute__((address_space(3))) void*)(sA + tid * 8), 16, 0, 0);
        __builtin_amdgcn_global_load_lds((const __attribute__((address_space(1))) void*)(Ap + a2 + k0),
                                         (__attribute__((address_space(3))) void*)(sA + 2048 + tid * 8), 16, 0, 0);
        __builtin_amdgcn_global_load_lds((const __attribute__((address_space(1))) void*)(Wp + k0),
                                         (__attribute__((address_space(3))) void*)(sB + tid * 8), 16, 0, 0);
        __builtin_amdgcn_global_load_lds((const __attribute__((address_space(1))) void*)(Wp + (long)64 * 768 + k0),
                                         (__attribute__((address_space(3))) void*)(sB + 2048 + tid * 8), 16, 0, 0);
        __syncthreads();
        bf16x8 aF[4], bF[4];
#pragma unroll
        for (int i = 0; i < 4; i++) {
            aF[i] = *(const bf16x8*)(sA + (wm + i * 16 + fr) * 32 + fq);
            bF[i] = *(const bf16x8*)(sB + (wn + i * 16 + fr) * 32 + fq);
        }
#pragma unroll
        for (int i = 0; i < 4; i++)
#pragma unroll
            for (int j = 0; j < 4; j++)
                acc[i][j] = __builtin_amdgcn_mfma_f32_16x16x32_bf16(aF[i], bF[j], acc[i][j], 0, 0, 0);
        __syncthreads();
    }
    float partl[4][4] = {};
#pragma unroll
    for (int j = 0; j < 4; j++) {
        const int col = bn * 128 + wn + j * 16 + fr;
        const float cv = cbias[col];
        const float wv = w2[col];
#pragma unroll
        for (int i = 0; i < 4; i++)
#pragma unroll
            for (int r = 0; r < 4; r++)
                partl[i][r] += fmaxf(acc[i][j][r] + cv, 0.f) * wv;
    }
#pragma unroll
    for (int i = 0; i < 4; i++)
#pragma unroll
        for (int r = 0; r < 4; r++) {
            float v = partl[i][r];
#pragma unroll
            for (int off = 8; off > 0; off >>= 1) v += __shfl_xor(v, off);
            if (fr == 0) atomicAdd(&rowsum[wm + i * 16 + rq + r], v);
        }
    __syncthreads();
    if (tid < 128) part[(long)bn * MROWS + bm * 128 + tid] = rowsum[tid];
}

// ---------------- broadcast: out[(l,s),:] = prob; 4 physical rows per block ----------------
__global__ __launch_bounds__(256) void bcast_kernel(const float* __restrict__ part,
                                                    const float* __restrict__ b2,
                                                    float* __restrict__ out) {
    const int tid = threadIdx.x;
    const long p0 = (long)blockIdx.x * 4;
    const float b2v = b2[0];
#pragma unroll
    for (int r = 0; r < 4; r++) {
        const long p = p0 + r;
        const float pv = part[p] + part[MROWS + p] + part[2 * MROWS + p] + b2v;
        float4* dst = (float4*)(out + ((p & 15) * S_DIM + (p >> 4)) * S_DIM);
        float4 v4 = make_float4(pv, pv, pv, pv);
        dst[tid] = v4;
        dst[tid + 256] = v4;
    }
}

extern "C" void kernel_launch(void* const* d_in, const int* in_sizes, int n_in,
                              void* d_out, int out_size, void* d_ws, size_t ws_size,
                              hipStream_t stream) {
    const float* features   = (const float*)d_in[0];
    const float* in_proj_b  = (const float*)d_in[2];
    const float* out_proj_b = (const float*)d_in[4];
    const float* b1 = (const float*)d_in[6];
    const float* w2 = (const float*)d_in[7];
    const float* b2 = (const float*)d_in[8];
    float* out = (float*)d_out;

    char* p = (char*)d_ws;
    u16* fbf = (u16*)p; p += (size_t)MROWS * E_DIM * 2;        // features bf16    50.3 MB
    u16* wib = (u16*)p; p += (size_t)QKV_LD * E_DIM * 2;       // in_proj_w bf16    3.5 MB
    u16* w1b = (u16*)p; p += (size_t)384 * E_DIM * 2;          // w1 bf16           0.6 MB
    u16* WoT = (u16*)p; p += (size_t)E_DIM * E_DIM * 2;        // out_proj_w^T bf16 1.2 MB
    u16* Gbf = (u16*)p; p += (size_t)384 * E_DIM * 2;          // G = W1@Wo bf16    0.6 MB
    float* cbuf  = (float*)p; p += 384 * 4;
    float* partb = (float*)p; p += (size_t)3 * MROWS * 4;      // per-panel row sums 384 KB
    float* zeros = (float*)p; p += 768 * 4;
    p = (char*)(((size_t)p + 255) & ~(size_t)255);
    u16* qkv = (u16*)p; p += (size_t)MROWS * QKV_LD * 2;       // qkv bf16 (s-major) 151 MB
    u16* ctx = qkv;                                            // attention writes over q cols

    hipMemsetAsync(zeros, 0, 768 * 4, stream);

    cvt_bf16<<<(MROWS * E_DIM / 4 + 255) / 256, 256, 0, stream>>>(features, fbf, MROWS * E_DIM / 4);
    cvt_bf16<<<(QKV_LD * E_DIM / 4 + 255) / 256, 256, 0, stream>>>((const float*)d_in[1], wib, QKV_LD * E_DIM / 4);
    cvt_bf16<<<(384 * E_DIM / 4 + 255) / 256, 256, 0, stream>>>((const float*)d_in[5], w1b, 384 * E_DIM / 4);
    transpose_cvt<<<dim3(24, 24), 256, 0, stream>>>((const float*)d_in[3], WoT);
    cbias_kernel<<<384, 256, 0, stream>>>((const float*)d_in[5], out_proj_b, b1, cbuf);

    // G = W1 @ Wo
    gemm_bt<false, false, false><<<dim3(6, 3), 256, 0, stream>>>(
        w1b, E_DIM, WoT, zeros, Gbf, E_DIM, E_DIM, E_DIM);
    // qkv = features @ in_proj_w^T + b, s-major
    gemm_bt<false, true, true><<<dim3(4608), 256, 0, stream>>>(
        fbf, E_DIM, wib, in_proj_b, qkv, QKV_LD, QKV_LD, E_DIM);
    // attention (in place into q-columns)
    attn_kernel<<<S_DIM * 2, 256, 0, stream>>>(qkv);
    // MLP panels -> partial row sums
    mlp_gemm<<<768, 256, 0, stream>>>(ctx, QKV_LD, Gbf, cbuf, w2, partb);
    // broadcast write
    bcast_kernel<<<MROWS / 4, 256, 0, stream>>>(partb, b2, out);
}

// Round 5
// 606.076 us; speedup vs baseline: 1.1595x; 1.0264x over previous
//
#include <hip/hip_runtime.h>

typedef unsigned short u16;
typedef __attribute__((ext_vector_type(8))) __bf16 bf16x8;
typedef __attribute__((ext_vector_type(4))) float floatx4;

#define B_DIM  16
#define S_DIM  2048
#define E_DIM  768
#define HEADS  8
#define DHEAD  96
#define MROWS  32768    // B_DIM * S_DIM
#define QKV_LD 2304     // 3*E_DIM
#define ATT_ST 392      // attn LDS row stride in u16

__device__ __forceinline__ u16 f2b(float f) {
    unsigned u = __float_as_uint(f);
    u += 0x7fffu + ((u >> 16) & 1u);   // RNE
    return (u16)(u >> 16);
}
__device__ __forceinline__ float blo(unsigned u) { return __uint_as_float(u << 16); }
__device__ __forceinline__ float bhi(unsigned u) { return __uint_as_float(u & 0xffff0000u); }

__device__ __forceinline__ void axpy8(float* acc, float p, uint4 v) {
    acc[0] += p * blo(v.x); acc[1] += p * bhi(v.x);
    acc[2] += p * blo(v.y); acc[3] += p * bhi(v.y);
    acc[4] += p * blo(v.z); acc[5] += p * bhi(v.z);
    acc[6] += p * blo(v.w); acc[7] += p * bhi(v.w);
}

// ---------------- merged prep: cvt fbf / wib / w1b, transpose WoT, cbias ----------------
#define PB0 24576   // fbf cvt blocks   (32768*768/4/256)
#define PB1 26304   // + wib 1728       (2304*768/4/256)
#define PB2 26592   // + w1b 288        (384*768/4/256)
#define PB3 27168   // + transpose 576  (24*24)
#define PB4 27552   // + cbias 384
__global__ __launch_bounds__(256) void prep(const float* __restrict__ features,
                                            const float* __restrict__ in_proj_w,
                                            const float* __restrict__ w1,
                                            const float* __restrict__ out_proj_w,
                                            const float* __restrict__ bo,
                                            const float* __restrict__ b1,
                                            u16* __restrict__ fbf, u16* __restrict__ wib,
                                            u16* __restrict__ w1b, u16* __restrict__ WoT,
                                            float* __restrict__ cbuf) {
    __shared__ float tsh[32][33];
    const int b = blockIdx.x, tid = threadIdx.x;
    if (b < PB2) {   // the three fp32->bf16 copies
        const float* src; u16* dst; long i;
        if (b < PB0)      { src = features;  dst = fbf; i = (long)b * 256 + tid; }
        else if (b < PB1) { src = in_proj_w; dst = wib; i = (long)(b - PB0) * 256 + tid; }
        else              { src = w1;        dst = w1b; i = (long)(b - PB1) * 256 + tid; }
        float4 f = ((const float4*)src)[i];
        ushort4 r;
        r.x = f2b(f.x); r.y = f2b(f.y); r.z = f2b(f.z); r.w = f2b(f.w);
        ((ushort4*)dst)[i] = r;
    } else if (b < PB3) {   // 768x768 transpose+cvt of out_proj_w
        const int t = b - PB2;
        const int bxT = t % 24, byT = t / 24;
        const int tx = tid & 31, ty = tid >> 5;
        int x = bxT * 32 + tx;
        int y = byT * 32 + ty;
#pragma unroll
        for (int j = 0; j < 4; j++) tsh[ty + j * 8][tx] = out_proj_w[(long)(y + j * 8) * 768 + x];
        __syncthreads();
        x = byT * 32 + tx;
        y = bxT * 32 + ty;
#pragma unroll
        for (int j = 0; j < 4; j++) WoT[(long)(y + j * 8) * 768 + x] = f2b(tsh[tx][ty + j * 8]);
    } else {   // cbias: c[n] = b1[n] + W1[n,:]·bo
        const int n = b - PB3;
        const float* row = w1 + (long)n * 768;
        float s = row[tid] * bo[tid] + row[tid + 256] * bo[tid + 256] + row[tid + 512] * bo[tid + 512];
#pragma unroll
        for (int off = 32; off > 0; off >>= 1) s += __shfl_xor(s, off);
        if ((tid & 63) == 0) tsh[0][tid >> 6] = s;
        __syncthreads();
        if (tid == 0) cbuf[n] = tsh[0][0] + tsh[0][1] + tsh[0][2] + tsh[0][3] + b1[n];
    }
}

// ---------------- bf16 MFMA GEMM: C[m,n] = sum_k A[m,k]*W[n,k] + bias[n], bf16 out ----------------
// PERM: store logical row m at physical row (m&2047)*16 + (m>>11)  (s-major)
// SWIZ (QKV shape only, 4608 linear blocks): per-XCD bm-group of 8, bn inner sweep, 4 phases.
template<bool PERM, bool SWIZ>
__global__ __launch_bounds__(256) void gemm_bt(const u16* __restrict__ A, int lda,
                                               const u16* __restrict__ W,
                                               const float* __restrict__ bias,
                                               u16* __restrict__ Cout, int ldc,
                                               int N, int K) {
    __shared__ __align__(16) u16 sA[128 * 32];
    __shared__ __align__(16) u16 sB[128 * 32];
    __shared__ __align__(16) u16 sC[32 * 132];   // epilogue staging, stride 132 breaks bank collisions
    const int tid  = threadIdx.x;
    int bn, bm;
    if (SWIZ) {
        const int bx  = blockIdx.x;
        const int xcd = bx & 7;
        const int q   = bx >> 3;        // 0..575
        const int s   = q / 144;        // 4 phases of 64 bm-rows
        const int r   = q % 144;        // 18 bn x 8 bm
        bn = r >> 3;
        bm = s * 64 + xcd * 8 + (r & 7);
    } else {
        bn = blockIdx.x;
        bm = blockIdx.y;
    }
    const int lane = tid & 63;
    const int wid  = tid >> 6;
    const int wm   = (wid >> 1) * 64;
    const int wn   = (wid & 1) * 64;
    const int ar = tid >> 2;
    const int ac = (tid & 3) * 8;
    const u16* Ap = A + (long)(bm * 128 + ar) * lda + ac;
    const u16* Wp = W + (long)(bn * 128 + ar) * K + ac;
    const long a2 = (long)64 * lda;
    const long w2 = (long)64 * K;

    floatx4 acc[4][4] = {};
    const int fr = lane & 15;
    const int fq = (lane >> 4) * 8;

    for (int k0 = 0; k0 < K; k0 += 32) {
        __builtin_amdgcn_global_load_lds((const __attribute__((address_space(1))) void*)(Ap + k0),
                                         (__attribute__((address_space(3))) void*)(sA + tid * 8), 16, 0, 0);
        __builtin_amdgcn_global_load_lds((const __attribute__((address_space(1))) void*)(Ap + a2 + k0),
                                         (__attribute__((address_space(3))) void*)(sA + 2048 + tid * 8), 16, 0, 0);
        __builtin_amdgcn_global_load_lds((const __attribute__((address_space(1))) void*)(Wp + k0),
                                         (__attribute__((address_space(3))) void*)(sB + tid * 8), 16, 0, 0);
        __builtin_amdgcn_global_load_lds((const __attribute__((address_space(1))) void*)(Wp + w2 + k0),
                                         (__attribute__((address_space(3))) void*)(sB + 2048 + tid * 8), 16, 0, 0);
        __syncthreads();

        bf16x8 aF[4], bF[4];
#pragma unroll
        for (int i = 0; i < 4; i++) {
            aF[i] = *(const bf16x8*)(sA + (wm + i * 16 + fr) * 32 + fq);
            bF[i] = *(const bf16x8*)(sB + (wn + i * 16 + fr) * 32 + fq);
        }
#pragma unroll
        for (int i = 0; i < 4; i++)
#pragma unroll
            for (int j = 0; j < 4; j++)
                acc[i][j] = __builtin_amdgcn_mfma_f32_16x16x32_bf16(aF[i], bF[j], acc[i][j], 0, 0, 0);
        __syncthreads();
    }

    // epilogue: stage 32-row slabs in LDS, store 256B-contiguous row segments.
    // C/D layout col=lane&15, row=(lane>>4)*4+r  [verified m89/m91]
    const int rq = (lane >> 4) * 4;
    float bvj[4];
#pragma unroll
    for (int j = 0; j < 4; j++)
        bvj[j] = bias ? bias[bn * 128 + wn + j * 16 + fr] : 0.f;
#pragma unroll
    for (int p = 0; p < 4; p++) {
        if ((p >> 1) == (wid >> 1)) {
#pragma unroll
            for (int ii = 0; ii < 2; ii++) {
                const int i = (p & 1) * 2 + ii;
#pragma unroll
                for (int j = 0; j < 4; j++) {
                    const int col = wn + j * 16 + fr;
#pragma unroll
                    for (int r = 0; r < 4; r++)
                        sC[(ii * 16 + rq + r) * 132 + col] = f2b(acc[i][j][r] + bvj[j]);
                }
            }
        }
        __syncthreads();
#pragma unroll
        for (int q2 = 0; q2 < 2; q2++) {
            const int lr = (tid >> 4) + q2 * 16;
            const int c  = tid & 15;
            uint4 v = *(const uint4*)(sC + lr * 132 + c * 8);
            const int rl = bm * 128 + p * 32 + lr;
            const long grow = PERM ? (long)(((rl & 2047) << 4) | (rl >> 11)) : (long)rl;
            *(uint4*)(Cout + grow * ldc + bn * 128 + c * 8) = v;
        }
        __syncthreads();
    }
}

// ---------------- attention: block = (s, head-half); MFMA scores + in-reg softmax ----------------
__global__ __launch_bounds__(256) void attn_kernel(u16* __restrict__ qkv) {
    __shared__ __align__(16) u16 sQ[16 * ATT_ST], sK[16 * ATT_ST], sV[16 * ATT_ST];
    __shared__ float sS[4][16][16];
    const int tid = threadIdx.x;
    const int s  = blockIdx.x >> 1;
    const int hh = blockIdx.x & 1;
    const u16* base = qkv + (long)s * 16 * QKV_LD + hh * 384;

#pragma unroll
    for (int it = 0; it < 9; it++) {
        const int i = it * 256 + tid;
        const int t = i / 768, rem = i % 768, l = rem / 48, c = rem % 48;
        const u16* src = base + (long)l * QKV_LD + t * E_DIM + c * 8;
        u16* dst = (t == 0 ? sQ : t == 1 ? sK : sV) + l * ATT_ST + c * 8;
        *(uint4*)dst = *(const uint4*)src;
    }
    __syncthreads();

    const int lane = tid & 63;
    const int w    = tid >> 6;
    const int fr   = lane & 15;
    const int fq   = (lane >> 4) * 8;
    floatx4 acc = {};
    const u16* qrow = sQ + fr * ATT_ST + w * DHEAD + fq;
    const u16* krow = sK + fr * ATT_ST + w * DHEAD + fq;
#pragma unroll
    for (int st = 0; st < 3; st++) {
        bf16x8 qa = *(const bf16x8*)(qrow + st * 32);
        bf16x8 kb = *(const bf16x8*)(krow + st * 32);
        acc = __builtin_amdgcn_mfma_f32_16x16x32_bf16(qa, kb, acc, 0, 0, 0);
    }
    const int rq = (lane >> 4) * 4;
#pragma unroll
    for (int r = 0; r < 4; r++) {
        float sc = acc[r] * 0.10206207261596577f;   // 1/sqrt(96)
        float mx = sc;
#pragma unroll
        for (int off = 8; off > 0; off >>= 1) mx = fmaxf(mx, __shfl_xor(mx, off));
        float e = __expf(sc - mx);
        float sum = e;
#pragma unroll
        for (int off = 8; off > 0; off >>= 1) sum += __shfl_xor(sum, off);
        sS[w][rq + r][fr] = e / sum;
    }
    __syncthreads();

#pragma unroll
    for (int j = 0; j < 3; j++) {
        const int task = j * 256 + tid;
        const int h = task / 192, rem = task % 192, ll = rem / 12, c = rem % 12;
        float a[8] = {};
#pragma unroll
        for (int mm = 0; mm < 16; mm++) {
            const float p = sS[h][ll][mm];
            uint4 vw = *(const uint4*)(sV + mm * ATT_ST + h * DHEAD + c * 8);
            axpy8(a, p, vw);
        }
        ushort4 o0, o1;
        o0.x = f2b(a[0]); o0.y = f2b(a[1]); o0.z = f2b(a[2]); o0.w = f2b(a[3]);
        o1.x = f2b(a[4]); o1.y = f2b(a[5]); o1.z = f2b(a[6]); o1.w = f2b(a[7]);
        u16* dst = qkv + ((long)s * 16 + ll) * QKV_LD + (hh * 4 + h) * DHEAD + c * 8;
        *(ushort4*)dst = o0;
        *(ushort4*)(dst + 4) = o1;
    }
}

// ---------------- MLP GEMM panel: part[panel][row] = sum_{n in panel} relu(ctx@G^T + c)[row,n]*w2[n] ----------------
__global__ __launch_bounds__(256) void mlp_gemm(const u16* __restrict__ A, int lda,
                                                const u16* __restrict__ G,
                                                const float* __restrict__ cbias,
                                                const float* __restrict__ w2,
                                                float* __restrict__ part) {
    __shared__ __align__(16) u16 sA[128 * 32];
    __shared__ __align__(16) u16 sB[128 * 32];
    __shared__ float rowsum[128];
    const int tid = threadIdx.x;
    const int bm  = blockIdx.x / 3;
    const int bn  = blockIdx.x % 3;
    if (tid < 128) rowsum[tid] = 0.f;
    const int lane = tid & 63;
    const int wid  = tid >> 6;
    const int wm   = (wid >> 1) * 64;
    const int wn   = (wid & 1) * 64;
    const int ar = tid >> 2;
    const int ac = (tid & 3) * 8;
    const u16* Ap = A + (long)(bm * 128 + ar) * lda + ac;
    const u16* Wp = G + (long)(bn * 128 + ar) * 768 + ac;
    const long a2 = (long)64 * lda;
    const int fr = lane & 15;
    const int fq = (lane >> 4) * 8;
    const int rq = (lane >> 4) * 4;

    floatx4 acc[4][4] = {};
    for (int k0 = 0; k0 < 768; k0 += 32) {
        __builtin_amdgcn_global_load_lds((const __attribute__((address_space(1))) void*)(Ap + k0),
                                         (__attribute__((address_space(3))) void*)(sA + tid * 8), 16, 0, 0);
        __builtin_amdgcn_global_load_lds((const __attribute__((address_space(1))) void*)(Ap + a2 + k0),
                                         (__attribute__((address_space(3))) void*)(sA + 2048 + tid * 8), 16, 0, 0);
        __builtin_amdgcn_global_load_lds((const __attribute__((address_space(1))) void*)(Wp + k0),
                                         (__attribute__((address_space(3))) void*)(sB + tid * 8), 16, 0, 0);
        __builtin_amdgcn_global_load_lds((const __attribute__((address_space(1))) void*)(Wp + (long)64 * 768 + k0),
                                         (__attribute__((address_space(3))) void*)(sB + 2048 + tid * 8), 16, 0, 0);
        __syncthreads();
        bf16x8 aF[4], bF[4];
#pragma unroll
        for (int i = 0; i < 4; i++) {
            aF[i] = *(const bf16x8*)(sA + (wm + i * 16 + fr) * 32 + fq);
            bF[i] = *(const bf16x8*)(sB + (wn + i * 16 + fr) * 32 + fq);
        }
#pragma unroll
        for (int i = 0; i < 4; i++)
#pragma unroll
            for (int j = 0; j < 4; j++)
                acc[i][j] = __builtin_amdgcn_mfma_f32_16x16x32_bf16(aF[i], bF[j], acc[i][j], 0, 0, 0);
        __syncthreads();
    }
    float partl[4][4] = {};
#pragma unroll
    for (int j = 0; j < 4; j++) {
        const int col = bn * 128 + wn + j * 16 + fr;
        const float cv = cbias[col];
        const float wv = w2[col];
#pragma unroll
        for (int i = 0; i < 4; i++)
#pragma unroll
            for (int r = 0; r < 4; r++)
                partl[i][r] += fmaxf(acc[i][j][r] + cv, 0.f) * wv;
    }
#pragma unroll
    for (int i = 0; i < 4; i++)
#pragma unroll
        for (int r = 0; r < 4; r++) {
            float v = partl[i][r];
#pragma unroll
            for (int off = 8; off > 0; off >>= 1) v += __shfl_xor(v, off);
            if (fr == 0) atomicAdd(&rowsum[wm + i * 16 + rq + r], v);
        }
    __syncthreads();
    if (tid < 128) part[(long)bn * MROWS + bm * 128 + tid] = rowsum[tid];
}

// ---------------- broadcast: out[(l,s),:] = prob; 4 physical rows per block ----------------
__global__ __launch_bounds__(256) void bcast_kernel(const float* __restrict__ part,
                                                    const float* __restrict__ b2,
                                                    float* __restrict__ out) {
    const int tid = threadIdx.x;
    const long p0 = (long)blockIdx.x * 4;
    const float b2v = b2[0];
#pragma unroll
    for (int r = 0; r < 4; r++) {
        const long p = p0 + r;
        const float pv = part[p] + part[MROWS + p] + part[2 * MROWS + p] + b2v;
        float4* dst = (float4*)(out + ((p & 15) * S_DIM + (p >> 4)) * S_DIM);
        float4 v4 = make_float4(pv, pv, pv, pv);
        dst[tid] = v4;
        dst[tid + 256] = v4;
    }
}

extern "C" void kernel_launch(void* const* d_in, const int* in_sizes, int n_in,
                              void* d_out, int out_size, void* d_ws, size_t ws_size,
                              hipStream_t stream) {
    const float* features   = (const float*)d_in[0];
    const float* in_proj_b  = (const float*)d_in[2];
    const float* out_proj_b = (const float*)d_in[4];
    const float* b1 = (const float*)d_in[6];
    const float* w2 = (const float*)d_in[7];
    const float* b2 = (const float*)d_in[8];
    float* out = (float*)d_out;

    char* p = (char*)d_ws;
    u16* fbf = (u16*)p; p += (size_t)MROWS * E_DIM * 2;        // features bf16    50.3 MB
    u16* wib = (u16*)p; p += (size_t)QKV_LD * E_DIM * 2;       // in_proj_w bf16    3.5 MB
    u16* w1b = (u16*)p; p += (size_t)384 * E_DIM * 2;          // w1 bf16           0.6 MB
    u16* WoT = (u16*)p; p += (size_t)E_DIM * E_DIM * 2;        // out_proj_w^T bf16 1.2 MB
    u16* Gbf = (u16*)p; p += (size_t)384 * E_DIM * 2;          // G = W1@Wo bf16    0.6 MB
    float* cbuf  = (float*)p; p += 384 * 4;
    float* partb = (float*)p; p += (size_t)3 * MROWS * 4;      // per-panel row sums 384 KB
    p = (char*)(((size_t)p + 255) & ~(size_t)255);
    u16* qkv = (u16*)p; p += (size_t)MROWS * QKV_LD * 2;       // qkv bf16 (s-major) 151 MB
    u16* ctx = qkv;                                            // attention writes over q cols

    // merged prep (3 cvts + transpose + cbias)
    prep<<<PB4, 256, 0, stream>>>(features, (const float*)d_in[1], (const float*)d_in[5],
                                  (const float*)d_in[3], out_proj_b, b1,
                                  fbf, wib, w1b, WoT, cbuf);
    // G = W1 @ Wo (no bias)
    gemm_bt<false, false><<<dim3(6, 3), 256, 0, stream>>>(
        w1b, E_DIM, WoT, nullptr, Gbf, E_DIM, E_DIM, E_DIM);
    // qkv = features @ in_proj_w^T + b, s-major, XCD swizzle v3
    gemm_bt<true, true><<<dim3(4608), 256, 0, stream>>>(
        fbf, E_DIM, wib, in_proj_b, qkv, QKV_LD, QKV_LD, E_DIM);
    // attention (in place into q-columns)
    attn_kernel<<<S_DIM * 2, 256, 0, stream>>>(qkv);
    // MLP panels -> partial row sums
    mlp_gemm<<<768, 256, 0, stream>>>(ctx, QKV_LD, Gbf, cbuf, w2, partb);
    // broadcast write
    bcast_kernel<<<MROWS / 4, 256, 0, stream>>>(partb, b2, out);
}

// Round 7
// 591.492 us; speedup vs baseline: 1.1881x; 1.0247x over previous
//
#include <hip/hip_runtime.h>

typedef unsigned short u16;
typedef __attribute__((ext_vector_type(8))) __bf16 bf16x8;
typedef __attribute__((ext_vector_type(4))) float floatx4;

#define B_DIM  16
#define S_DIM  2048
#define E_DIM  768
#define HEADS  8
#define DHEAD  96
#define MROWS  32768    // B_DIM * S_DIM
#define QKV_LD 2304     // 3*E_DIM
#define ATT_ST 392      // attn LDS row stride in u16

#define GLDS(gp, lp) __builtin_amdgcn_global_load_lds( \
    (const __attribute__((address_space(1))) void*)(gp), \
    (__attribute__((address_space(3))) void*)(lp), 16, 0, 0)

__device__ __forceinline__ u16 f2b(float f) {
    unsigned u = __float_as_uint(f);
    u += 0x7fffu + ((u >> 16) & 1u);   // RNE
    return (u16)(u >> 16);
}
__device__ __forceinline__ float blo(unsigned u) { return __uint_as_float(u << 16); }
__device__ __forceinline__ float bhi(unsigned u) { return __uint_as_float(u & 0xffff0000u); }

__device__ __forceinline__ void axpy8(float* acc, float p, uint4 v) {
    acc[0] += p * blo(v.x); acc[1] += p * bhi(v.x);
    acc[2] += p * blo(v.y); acc[3] += p * bhi(v.y);
    acc[4] += p * blo(v.z); acc[5] += p * bhi(v.z);
    acc[6] += p * blo(v.w); acc[7] += p * bhi(v.w);
}

// ---------------- merged prep: cvt fbf / wib / w1b, transpose WoT, cbias ----------------
#define PB0 24576   // fbf cvt blocks   (32768*768/4/256)
#define PB1 26304   // + wib 1728       (2304*768/4/256)
#define PB2 26592   // + w1b 288        (384*768/4/256)
#define PB3 27168   // + transpose 576  (24*24)
#define PB4 27552   // + cbias 384
__global__ __launch_bounds__(256) void prep(const float* __restrict__ features,
                                            const float* __restrict__ in_proj_w,
                                            const float* __restrict__ w1,
                                            const float* __restrict__ out_proj_w,
                                            const float* __restrict__ bo,
                                            const float* __restrict__ b1,
                                            u16* __restrict__ fbf, u16* __restrict__ wib,
                                            u16* __restrict__ w1b, u16* __restrict__ WoT,
                                            float* __restrict__ cbuf) {
    __shared__ float tsh[32][33];
    const int b = blockIdx.x, tid = threadIdx.x;
    if (b < PB2) {   // the three fp32->bf16 copies
        const float* src; u16* dst; long i;
        if (b < PB0)      { src = features;  dst = fbf; i = (long)b * 256 + tid; }
        else if (b < PB1) { src = in_proj_w; dst = wib; i = (long)(b - PB0) * 256 + tid; }
        else              { src = w1;        dst = w1b; i = (long)(b - PB1) * 256 + tid; }
        float4 f = ((const float4*)src)[i];
        ushort4 r;
        r.x = f2b(f.x); r.y = f2b(f.y); r.z = f2b(f.z); r.w = f2b(f.w);
        ((ushort4*)dst)[i] = r;
    } else if (b < PB3) {   // 768x768 transpose+cvt of out_proj_w
        const int t = b - PB2;
        const int bxT = t % 24, byT = t / 24;
        const int tx = tid & 31, ty = tid >> 5;
        int x = bxT * 32 + tx;
        int y = byT * 32 + ty;
#pragma unroll
        for (int j = 0; j < 4; j++) tsh[ty + j * 8][tx] = out_proj_w[(long)(y + j * 8) * 768 + x];
        __syncthreads();
        x = byT * 32 + tx;
        y = bxT * 32 + ty;
#pragma unroll
        for (int j = 0; j < 4; j++) WoT[(long)(y + j * 8) * 768 + x] = f2b(tsh[tx][ty + j * 8]);
    } else {   // cbias: c[n] = b1[n] + W1[n,:]·bo
        const int n = b - PB3;
        const float* row = w1 + (long)n * 768;
        float s = row[tid] * bo[tid] + row[tid + 256] * bo[tid + 256] + row[tid + 512] * bo[tid + 512];
#pragma unroll
        for (int off = 32; off > 0; off >>= 1) s += __shfl_xor(s, off);
        if ((tid & 63) == 0) tsh[0][tid >> 6] = s;
        __syncthreads();
        if (tid == 0) cbuf[n] = tsh[0][0] + tsh[0][1] + tsh[0][2] + tsh[0][3] + b1[n];
    }
}

// ---------------- bf16 MFMA GEMM, BK=64 (two side-by-side BK=32 panels) ----------------
// C[m,n] = sum_k A[m,k]*W[n,k] + bias[n], bf16 out. K must be a multiple of 64.
// PERM: store logical row m at physical row (m&2047)*16 + (m>>11)  (s-major)
// SWIZ (QKV shape only, 4608 linear blocks): per-XCD bm-group of 8, bn inner sweep, 4 phases.
template<bool PERM, bool SWIZ>
__global__ __launch_bounds__(256) void gemm_bt(const u16* __restrict__ A, int lda,
                                               const u16* __restrict__ W,
                                               const float* __restrict__ bias,
                                               u16* __restrict__ Cout, int ldc,
                                               int N, int K) {
    __shared__ __align__(16) u16 sA[2 * 128 * 32];   // [half][row][32]
    __shared__ __align__(16) u16 sB[2 * 128 * 32];
    __shared__ __align__(16) u16 sC[32 * 132];       // epilogue staging
    const int tid  = threadIdx.x;
    int bn, bm;
    if (SWIZ) {
        const int bx  = blockIdx.x;
        const int xcd = bx & 7;
        const int q   = bx >> 3;        // 0..575
        const int s   = q / 144;        // 4 phases of 64 bm-rows
        const int r   = q % 144;        // 18 bn x 8 bm
        bn = r >> 3;
        bm = s * 64 + xcd * 8 + (r & 7);
    } else {
        bn = blockIdx.x;
        bm = blockIdx.y;
    }
    const int lane = tid & 63;
    const int wid  = tid >> 6;
    const int wm   = (wid >> 1) * 64;
    const int wn   = (wid & 1) * 64;
    const int ar = tid >> 2;
    const int ac = (tid & 3) * 8;
    const u16* Ap = A + (long)(bm * 128 + ar) * lda + ac;
    const u16* Wp = W + (long)(bn * 128 + ar) * K + ac;
    const long a2 = (long)64 * lda;
    const long w2 = (long)64 * K;

    floatx4 acc[4][4] = {};
    const int fr = lane & 15;
    const int fq = (lane >> 4) * 8;

    for (int k0 = 0; k0 < K; k0 += 64) {
#pragma unroll
        for (int h = 0; h < 2; h++) {
            GLDS(Ap + k0 + h * 32,      sA + h * 4096 + tid * 8);
            GLDS(Ap + a2 + k0 + h * 32, sA + h * 4096 + 2048 + tid * 8);
            GLDS(Wp + k0 + h * 32,      sB + h * 4096 + tid * 8);
            GLDS(Wp + w2 + k0 + h * 32, sB + h * 4096 + 2048 + tid * 8);
        }
        __syncthreads();   // single vmcnt(0) drain per 64 K
#pragma unroll
        for (int h = 0; h < 2; h++) {
            bf16x8 aF[4], bF[4];
#pragma unroll
            for (int i = 0; i < 4; i++) {
                aF[i] = *(const bf16x8*)(sA + h * 4096 + (wm + i * 16 + fr) * 32 + fq);
                bF[i] = *(const bf16x8*)(sB + h * 4096 + (wn + i * 16 + fr) * 32 + fq);
            }
#pragma unroll
            for (int i = 0; i < 4; i++)
#pragma unroll
                for (int j = 0; j < 4; j++)
                    acc[i][j] = __builtin_amdgcn_mfma_f32_16x16x32_bf16(aF[i], bF[j], acc[i][j], 0, 0, 0);
        }
        __syncthreads();
    }

    // epilogue: stage 32-row slabs in LDS, store 256B-contiguous row segments.
    // C/D layout col=lane&15, row=(lane>>4)*4+r  [verified m89/m91]
    const int rq = (lane >> 4) * 4;
    float bvj[4];
#pragma unroll
    for (int j = 0; j < 4; j++)
        bvj[j] = bias ? bias[bn * 128 + wn + j * 16 + fr] : 0.f;
#pragma unroll
    for (int p = 0; p < 4; p++) {
        if ((p >> 1) == (wid >> 1)) {
#pragma unroll
            for (int ii = 0; ii < 2; ii++) {
                const int i = (p & 1) * 2 + ii;
#pragma unroll
                for (int j = 0; j < 4; j++) {
                    const int col = wn + j * 16 + fr;
#pragma unroll
                    for (int r = 0; r < 4; r++)
                        sC[(ii * 16 + rq + r) * 132 + col] = f2b(acc[i][j][r] + bvj[j]);
                }
            }
        }
        __syncthreads();
#pragma unroll
        for (int q2 = 0; q2 < 2; q2++) {
            const int lr = (tid >> 4) + q2 * 16;
            const int c  = tid & 15;
            uint4 v = *(const uint4*)(sC + lr * 132 + c * 8);
            const int rl = bm * 128 + p * 32 + lr;
            const long grow = PERM ? (long)(((rl & 2047) << 4) | (rl >> 11)) : (long)rl;
            *(uint4*)(Cout + grow * ldc + bn * 128 + c * 8) = v;
        }
        __syncthreads();
    }
}

// ---------------- attention: block = (s, head-half); MFMA scores + in-reg softmax ----------------
__global__ __launch_bounds__(256) void attn_kernel(u16* __restrict__ qkv) {
    __shared__ __align__(16) u16 sQ[16 * ATT_ST], sK[16 * ATT_ST], sV[16 * ATT_ST];
    __shared__ float sS[4][16][16];
    const int tid = threadIdx.x;
    const int s  = blockIdx.x >> 1;
    const int hh = blockIdx.x & 1;
    const u16* base = qkv + (long)s * 16 * QKV_LD + hh * 384;

#pragma unroll
    for (int it = 0; it < 9; it++) {
        const int i = it * 256 + tid;
        const int t = i / 768, rem = i % 768, l = rem / 48, c = rem % 48;
        const u16* src = base + (long)l * QKV_LD + t * E_DIM + c * 8;
        u16* dst = (t == 0 ? sQ : t == 1 ? sK : sV) + l * ATT_ST + c * 8;
        *(uint4*)dst = *(const uint4*)src;
    }
    __syncthreads();

    const int lane = tid & 63;
    const int w    = tid >> 6;
    const int fr   = lane & 15;
    const int fq   = (lane >> 4) * 8;
    floatx4 acc = {};
    const u16* qrow = sQ + fr * ATT_ST + w * DHEAD + fq;
    const u16* krow = sK + fr * ATT_ST + w * DHEAD + fq;
#pragma unroll
    for (int st = 0; st < 3; st++) {
        bf16x8 qa = *(const bf16x8*)(qrow + st * 32);
        bf16x8 kb = *(const bf16x8*)(krow + st * 32);
        acc = __builtin_amdgcn_mfma_f32_16x16x32_bf16(qa, kb, acc, 0, 0, 0);
    }
    const int rq = (lane >> 4) * 4;
#pragma unroll
    for (int r = 0; r < 4; r++) {
        float sc = acc[r] * 0.10206207261596577f;   // 1/sqrt(96)
        float mx = sc;
#pragma unroll
        for (int off = 8; off > 0; off >>= 1) mx = fmaxf(mx, __shfl_xor(mx, off));
        float e = __expf(sc - mx);
        float sum = e;
#pragma unroll
        for (int off = 8; off > 0; off >>= 1) sum += __shfl_xor(sum, off);
        sS[w][rq + r][fr] = e / sum;
    }
    __syncthreads();

#pragma unroll
    for (int j = 0; j < 3; j++) {
        const int task = j * 256 + tid;
        const int h = task / 192, rem = task % 192, ll = rem / 12, c = rem % 12;
        float a[8] = {};
#pragma unroll
        for (int mm = 0; mm < 16; mm++) {
            const float p = sS[h][ll][mm];
            uint4 vw = *(const uint4*)(sV + mm * ATT_ST + h * DHEAD + c * 8);
            axpy8(a, p, vw);
        }
        ushort4 o0, o1;
        o0.x = f2b(a[0]); o0.y = f2b(a[1]); o0.z = f2b(a[2]); o0.w = f2b(a[3]);
        o1.x = f2b(a[4]); o1.y = f2b(a[5]); o1.z = f2b(a[6]); o1.w = f2b(a[7]);
        u16* dst = qkv + ((long)s * 16 + ll) * QKV_LD + (hh * 4 + h) * DHEAD + c * 8;
        *(ushort4*)dst = o0;
        *(ushort4*)(dst + 4) = o1;
    }
}

// ---------------- MLP GEMM panel (BK=64): part[panel][row] = sum_n relu(ctx@G^T + c)[row,n]*w2[n] ----------------
__global__ __launch_bounds__(256) void mlp_gemm(const u16* __restrict__ A, int lda,
                                                const u16* __restrict__ G,
                                                const float* __restrict__ cbias,
                                                const float* __restrict__ w2,
                                                float* __restrict__ part) {
    __shared__ __align__(16) u16 sA[2 * 128 * 32];
    __shared__ __align__(16) u16 sB[2 * 128 * 32];
    __shared__ float rowsum[128];
    const int tid = threadIdx.x;
    const int bm  = blockIdx.x / 3;
    const int bn  = blockIdx.x % 3;
    if (tid < 128) rowsum[tid] = 0.f;
    const int lane = tid & 63;
    const int wid  = tid >> 6;
    const int wm   = (wid >> 1) * 64;
    const int wn   = (wid & 1) * 64;
    const int ar = tid >> 2;
    const int ac = (tid & 3) * 8;
    const u16* Ap = A + (long)(bm * 128 + ar) * lda + ac;
    const u16* Wp = G + (long)(bn * 128 + ar) * 768 + ac;
    const long a2 = (long)64 * lda;
    const long w2s = (long)64 * 768;
    const int fr = lane & 15;
    const int fq = (lane >> 4) * 8;
    const int rq = (lane >> 4) * 4;

    floatx4 acc[4][4] = {};
    for (int k0 = 0; k0 < 768; k0 += 64) {
#pragma unroll
        for (int h = 0; h < 2; h++) {
            GLDS(Ap + k0 + h * 32,       sA + h * 4096 + tid * 8);
            GLDS(Ap + a2 + k0 + h * 32,  sA + h * 4096 + 2048 + tid * 8);
            GLDS(Wp + k0 + h * 32,       sB + h * 4096 + tid * 8);
            GLDS(Wp + w2s + k0 + h * 32, sB + h * 4096 + 2048 + tid * 8);
        }
        __syncthreads();
#pragma unroll
        for (int h = 0; h < 2; h++) {
            bf16x8 aF[4], bF[4];
#pragma unroll
            for (int i = 0; i < 4; i++) {
                aF[i] = *(const bf16x8*)(sA + h * 4096 + (wm + i * 16 + fr) * 32 + fq);
                bF[i] = *(const bf16x8*)(sB + h * 4096 + (wn + i * 16 + fr) * 32 + fq);
            }
#pragma unroll
            for (int i = 0; i < 4; i++)
#pragma unroll
                for (int j = 0; j < 4; j++)
                    acc[i][j] = __builtin_amdgcn_mfma_f32_16x16x32_bf16(aF[i], bF[j], acc[i][j], 0, 0, 0);
        }
        __syncthreads();
    }
    float partl[4][4] = {};
#pragma unroll
    for (int j = 0; j < 4; j++) {
        const int col = bn * 128 + wn + j * 16 + fr;
        const float cv = cbias[col];
        const float wv = w2[col];
#pragma unroll
        for (int i = 0; i < 4; i++)
#pragma unroll
            for (int r = 0; r < 4; r++)
                partl[i][r] += fmaxf(acc[i][j][r] + cv, 0.f) * wv;
    }
#pragma unroll
    for (int i = 0; i < 4; i++)
#pragma unroll
        for (int r = 0; r < 4; r++) {
            float v = partl[i][r];
#pragma unroll
            for (int off = 8; off > 0; off >>= 1) v += __shfl_xor(v, off);
            if (fr == 0) atomicAdd(&rowsum[wm + i * 16 + rq + r], v);
        }
    __syncthreads();
    if (tid < 128) part[(long)bn * MROWS + bm * 128 + tid] = rowsum[tid];
}

// ---------------- broadcast: block = one s; 16 rows, nontemporal streaming stores ----------------
__global__ __launch_bounds__(256) void bcast_kernel(const float* __restrict__ part,
                                                    const float* __restrict__ b2,
                                                    float* __restrict__ out) {
    const int tid = threadIdx.x;
    const long s  = blockIdx.x;
    const float b2v = b2[0];
#pragma unroll
    for (int l = 0; l < 16; l++) {
        const long p = s * 16 + l;
        const float pv = part[p] + part[MROWS + p] + part[2 * MROWS + p] + b2v;
        floatx4 v4 = {pv, pv, pv, pv};
        floatx4* dst = (floatx4*)(out + ((long)l * S_DIM + s) * S_DIM);
        __builtin_nontemporal_store(v4, dst + tid);
        __builtin_nontemporal_store(v4, dst + tid + 256);
    }
}

extern "C" void kernel_launch(void* const* d_in, const int* in_sizes, int n_in,
                              void* d_out, int out_size, void* d_ws, size_t ws_size,
                              hipStream_t stream) {
    const float* features   = (const float*)d_in[0];
    const float* in_proj_b  = (const float*)d_in[2];
    const float* out_proj_b = (const float*)d_in[4];
    const float* b1 = (const float*)d_in[6];
    const float* w2 = (const float*)d_in[7];
    const float* b2 = (const float*)d_in[8];
    float* out = (float*)d_out;

    char* p = (char*)d_ws;
    u16* fbf = (u16*)p; p += (size_t)MROWS * E_DIM * 2;        // features bf16    50.3 MB
    u16* wib = (u16*)p; p += (size_t)QKV_LD * E_DIM * 2;       // in_proj_w bf16    3.5 MB
    u16* w1b = (u16*)p; p += (size_t)384 * E_DIM * 2;          // w1 bf16           0.6 MB
    u16* WoT = (u16*)p; p += (size_t)E_DIM * E_DIM * 2;        // out_proj_w^T bf16 1.2 MB
    u16* Gbf = (u16*)p; p += (size_t)384 * E_DIM * 2;          // G = W1@Wo bf16    0.6 MB
    float* cbuf  = (float*)p; p += 384 * 4;
    float* partb = (float*)p; p += (size_t)3 * MROWS * 4;      // per-panel row sums 384 KB
    p = (char*)(((size_t)p + 255) & ~(size_t)255);
    u16* qkv = (u16*)p; p += (size_t)MROWS * QKV_LD * 2;       // qkv bf16 (s-major) 151 MB
    u16* ctx = qkv;                                            // attention writes over q cols

    // merged prep (3 cvts + transpose + cbias)
    prep<<<PB4, 256, 0, stream>>>(features, (const float*)d_in[1], (const float*)d_in[5],
                                  (const float*)d_in[3], out_proj_b, b1,
                                  fbf, wib, w1b, WoT, cbuf);
    // G = W1 @ Wo (no bias)
    gemm_bt<false, false><<<dim3(6, 3), 256, 0, stream>>>(
        w1b, E_DIM, WoT, nullptr, Gbf, E_DIM, E_DIM, E_DIM);
    // qkv = features @ in_proj_w^T + b, s-major, XCD swizzle v3
    gemm_bt<true, true><<<dim3(4608), 256, 0, stream>>>(
        fbf, E_DIM, wib, in_proj_b, qkv, QKV_LD, QKV_LD, E_DIM);
    // attention (in place into q-columns)
    attn_kernel<<<S_DIM * 2, 256, 0, stream>>>(qkv);
    // MLP panels -> partial row sums
    mlp_gemm<<<768, 256, 0, stream>>>(ctx, QKV_LD, Gbf, cbuf, w2, partb);
    // broadcast write
    bcast_kernel<<<S_DIM, 256, 0, stream>>>(partb, b2, out);
}

// Round 8
// 579.867 us; speedup vs baseline: 1.2119x; 1.0200x over previous
//
#include <hip/hip_runtime.h>

typedef unsigned short u16;
typedef __attribute__((ext_vector_type(8))) __bf16 bf16x8;
typedef __attribute__((ext_vector_type(4))) float floatx4;

#define B_DIM  16
#define S_DIM  2048
#define E_DIM  768
#define HEADS  8
#define DHEAD  96
#define MROWS  32768    // B_DIM * S_DIM
#define QKV_LD 2304     // 3*E_DIM
#define ATT_ST 392      // attn LDS row stride in u16

#define GLDS(gp, lp) __builtin_amdgcn_global_load_lds( \
    (const __attribute__((address_space(1))) void*)(gp), \
    (__attribute__((address_space(3))) void*)(lp), 16, 0, 0)

__device__ __forceinline__ u16 f2b(float f) {
    unsigned u = __float_as_uint(f);
    u += 0x7fffu + ((u >> 16) & 1u);   // RNE
    return (u16)(u >> 16);
}
__device__ __forceinline__ float blo(unsigned u) { return __uint_as_float(u << 16); }
__device__ __forceinline__ float bhi(unsigned u) { return __uint_as_float(u & 0xffff0000u); }

__device__ __forceinline__ void axpy8(float* acc, float p, uint4 v) {
    acc[0] += p * blo(v.x); acc[1] += p * bhi(v.x);
    acc[2] += p * blo(v.y); acc[3] += p * bhi(v.y);
    acc[4] += p * blo(v.z); acc[5] += p * bhi(v.z);
    acc[6] += p * blo(v.w); acc[7] += p * bhi(v.w);
}

// ---------------- merged prep: cvt fbf / wib / w1b, transpose WoT, cbias ----------------
#define PB0 24576   // fbf cvt blocks   (32768*768/4/256)
#define PB1 26304   // + wib 1728       (2304*768/4/256)
#define PB2 26592   // + w1b 288        (384*768/4/256)
#define PB3 27168   // + transpose 576  (24*24)
#define PB4 27552   // + cbias 384
__global__ __launch_bounds__(256) void prep(const float* __restrict__ features,
                                            const float* __restrict__ in_proj_w,
                                            const float* __restrict__ w1,
                                            const float* __restrict__ out_proj_w,
                                            const float* __restrict__ bo,
                                            const float* __restrict__ b1,
                                            u16* __restrict__ fbf, u16* __restrict__ wib,
                                            u16* __restrict__ w1b, u16* __restrict__ WoT,
                                            float* __restrict__ cbuf) {
    __shared__ float tsh[32][33];
    const int b = blockIdx.x, tid = threadIdx.x;
    if (b < PB2) {   // the three fp32->bf16 copies
        const float* src; u16* dst; long i;
        if (b < PB0)      { src = features;  dst = fbf; i = (long)b * 256 + tid; }
        else if (b < PB1) { src = in_proj_w; dst = wib; i = (long)(b - PB0) * 256 + tid; }
        else              { src = w1;        dst = w1b; i = (long)(b - PB1) * 256 + tid; }
        float4 f = ((const float4*)src)[i];
        ushort4 r;
        r.x = f2b(f.x); r.y = f2b(f.y); r.z = f2b(f.z); r.w = f2b(f.w);
        ((ushort4*)dst)[i] = r;
    } else if (b < PB3) {   // 768x768 transpose+cvt of out_proj_w
        const int t = b - PB2;
        const int bxT = t % 24, byT = t / 24;
        const int tx = tid & 31, ty = tid >> 5;
        int x = bxT * 32 + tx;
        int y = byT * 32 + ty;
#pragma unroll
        for (int j = 0; j < 4; j++) tsh[ty + j * 8][tx] = out_proj_w[(long)(y + j * 8) * 768 + x];
        __syncthreads();
        x = byT * 32 + tx;
        y = bxT * 32 + ty;
#pragma unroll
        for (int j = 0; j < 4; j++) WoT[(long)(y + j * 8) * 768 + x] = f2b(tsh[tx][ty + j * 8]);
    } else {   // cbias: c[n] = b1[n] + W1[n,:]·bo
        const int n = b - PB3;
        const float* row = w1 + (long)n * 768;
        float s = row[tid] * bo[tid] + row[tid + 256] * bo[tid + 256] + row[tid + 512] * bo[tid + 512];
#pragma unroll
        for (int off = 32; off > 0; off >>= 1) s += __shfl_xor(s, off);
        if ((tid & 63) == 0) tsh[0][tid >> 6] = s;
        __syncthreads();
        if (tid == 0) cbuf[n] = tsh[0][0] + tsh[0][1] + tsh[0][2] + tsh[0][3] + b1[n];
    }
}

// ---------------- merged QKV + G GEMM (BK=64), bf16 MFMA ----------------
// Blocks [0,18): G = W1 @ Wo  (A=w1b 384x768, W=WoT, no bias, no perm)
// Blocks [18,4626): qkv = features @ in_proj_w^T + b, s-major perm, XCD swizzle.
__global__ __launch_bounds__(256) void qkv_g_kernel(const u16* __restrict__ A, int lda,
                                                    const u16* __restrict__ W,
                                                    const float* __restrict__ bias,
                                                    u16* __restrict__ Cout, int ldc, int K,
                                                    const u16* __restrict__ gA,
                                                    const u16* __restrict__ gW,
                                                    u16* __restrict__ gC) {
    __shared__ __align__(16) u16 sA[2 * 128 * 32];   // [half][row][32]
    __shared__ __align__(16) u16 sB[2 * 128 * 32];
    __shared__ __align__(16) u16 sC[32 * 132];       // epilogue staging
    const int tid = threadIdx.x;
    const int bx  = blockIdx.x;
    int bn, bm, lda_, ldc_, K_;
    const u16 *Aa, *Ww; const float* bs; u16* Co; bool perm;
    if (bx < 18) {           // G block (runs first, overlaps the QKV wave)
        bn = bx % 6; bm = bx / 6;
        Aa = gA; Ww = gW; bs = nullptr; Co = gC;
        lda_ = 768; ldc_ = 768; K_ = 768; perm = false;
    } else {                 // QKV block, XCD swizzle v3
        const int b2  = bx - 18;
        const int xcd = b2 & 7;
        const int q   = b2 >> 3;        // 0..575
        const int s   = q / 144;        // 4 phases of 64 bm-rows
        const int r   = q % 144;        // 18 bn x 8 bm
        bn = r >> 3;
        bm = s * 64 + xcd * 8 + (r & 7);
        Aa = A; Ww = W; bs = bias; Co = Cout;
        lda_ = lda; ldc_ = ldc; K_ = K; perm = true;
    }
    const int lane = tid & 63;
    const int wid  = tid >> 6;
    const int wm   = (wid >> 1) * 64;
    const int wn   = (wid & 1) * 64;
    const int ar = tid >> 2;
    const int ac = (tid & 3) * 8;
    const u16* Ap = Aa + (long)(bm * 128 + ar) * lda_ + ac;
    const u16* Wp = Ww + (long)(bn * 128 + ar) * K_ + ac;
    const long a2 = (long)64 * lda_;
    const long w2 = (long)64 * K_;

    floatx4 acc[4][4] = {};
    const int fr = lane & 15;
    const int fq = (lane >> 4) * 8;

    for (int k0 = 0; k0 < K_; k0 += 64) {
#pragma unroll
        for (int h = 0; h < 2; h++) {
            GLDS(Ap + k0 + h * 32,      sA + h * 4096 + tid * 8);
            GLDS(Ap + a2 + k0 + h * 32, sA + h * 4096 + 2048 + tid * 8);
            GLDS(Wp + k0 + h * 32,      sB + h * 4096 + tid * 8);
            GLDS(Wp + w2 + k0 + h * 32, sB + h * 4096 + 2048 + tid * 8);
        }
        __syncthreads();   // single vmcnt(0) drain per 64 K
#pragma unroll
        for (int h = 0; h < 2; h++) {
            bf16x8 aF[4], bF[4];
#pragma unroll
            for (int i = 0; i < 4; i++) {
                aF[i] = *(const bf16x8*)(sA + h * 4096 + (wm + i * 16 + fr) * 32 + fq);
                bF[i] = *(const bf16x8*)(sB + h * 4096 + (wn + i * 16 + fr) * 32 + fq);
            }
#pragma unroll
            for (int i = 0; i < 4; i++)
#pragma unroll
                for (int j = 0; j < 4; j++)
                    acc[i][j] = __builtin_amdgcn_mfma_f32_16x16x32_bf16(aF[i], bF[j], acc[i][j], 0, 0, 0);
        }
        __syncthreads();
    }

    // epilogue: stage 32-row slabs in LDS, store 256B-contiguous row segments.
    // C/D layout col=lane&15, row=(lane>>4)*4+r  [verified m89/m91]
    const int rq = (lane >> 4) * 4;
    float bvj[4];
#pragma unroll
    for (int j = 0; j < 4; j++)
        bvj[j] = bs ? bs[bn * 128 + wn + j * 16 + fr] : 0.f;
#pragma unroll
    for (int p = 0; p < 4; p++) {
        if ((p >> 1) == (wid >> 1)) {
#pragma unroll
            for (int ii = 0; ii < 2; ii++) {
                const int i = (p & 1) * 2 + ii;
#pragma unroll
                for (int j = 0; j < 4; j++) {
                    const int col = wn + j * 16 + fr;
#pragma unroll
                    for (int r = 0; r < 4; r++)
                        sC[(ii * 16 + rq + r) * 132 + col] = f2b(acc[i][j][r] + bvj[j]);
                }
            }
        }
        __syncthreads();
#pragma unroll
        for (int q2 = 0; q2 < 2; q2++) {
            const int lr = (tid >> 4) + q2 * 16;
            const int c  = tid & 15;
            uint4 v = *(const uint4*)(sC + lr * 132 + c * 8);
            const int rl = bm * 128 + p * 32 + lr;
            const long grow = perm ? (long)(((rl & 2047) << 4) | (rl >> 11)) : (long)rl;
            *(uint4*)(Co + grow * ldc_ + bn * 128 + c * 8) = v;
        }
        __syncthreads();
    }
}

// ---------------- attention: block = (s, head-half); MFMA scores + in-reg softmax ----------------
// XCD-aligned: s-group (s>>6)&7 was written by QKV blocks on XCD (bm>>3)&7 = (s>>6)&7,
// so map blockIdx so that bx&7 == (s>>6)&7  ->  qkv rows read from the local XCD's L2.
__global__ __launch_bounds__(256) void attn_kernel(u16* __restrict__ qkv) {
    __shared__ __align__(16) u16 sQ[16 * ATT_ST], sK[16 * ATT_ST], sV[16 * ATT_ST];
    __shared__ float sS[4][16][16];
    const int tid = threadIdx.x;
    const int bx  = blockIdx.x;
    const int xcd   = bx & 7;
    const int rest  = bx >> 3;          // 0..511
    const int hh    = rest & 1;
    const int inner = (rest >> 1) & 63;
    const int outer = rest >> 7;        // 0..3
    const int s = (outer << 9) | (xcd << 6) | inner;
    const u16* base = qkv + (long)s * 16 * QKV_LD + hh * 384;

#pragma unroll
    for (int it = 0; it < 9; it++) {
        const int i = it * 256 + tid;
        const int t = i / 768, rem = i % 768, l = rem / 48, c = rem % 48;
        const u16* src = base + (long)l * QKV_LD + t * E_DIM + c * 8;
        u16* dst = (t == 0 ? sQ : t == 1 ? sK : sV) + l * ATT_ST + c * 8;
        *(uint4*)dst = *(const uint4*)src;
    }
    __syncthreads();

    const int lane = tid & 63;
    const int w    = tid >> 6;
    const int fr   = lane & 15;
    const int fq   = (lane >> 4) * 8;
    floatx4 acc = {};
    const u16* qrow = sQ + fr * ATT_ST + w * DHEAD + fq;
    const u16* krow = sK + fr * ATT_ST + w * DHEAD + fq;
#pragma unroll
    for (int st = 0; st < 3; st++) {
        bf16x8 qa = *(const bf16x8*)(qrow + st * 32);
        bf16x8 kb = *(const bf16x8*)(krow + st * 32);
        acc = __builtin_amdgcn_mfma_f32_16x16x32_bf16(qa, kb, acc, 0, 0, 0);
    }
    const int rq = (lane >> 4) * 4;
#pragma unroll
    for (int r = 0; r < 4; r++) {
        float sc = acc[r] * 0.10206207261596577f;   // 1/sqrt(96)
        float mx = sc;
#pragma unroll
        for (int off = 8; off > 0; off >>= 1) mx = fmaxf(mx, __shfl_xor(mx, off));
        float e = __expf(sc - mx);
        float sum = e;
#pragma unroll
        for (int off = 8; off > 0; off >>= 1) sum += __shfl_xor(sum, off);
        sS[w][rq + r][fr] = e / sum;
    }
    __syncthreads();

#pragma unroll
    for (int j = 0; j < 3; j++) {
        const int task = j * 256 + tid;
        const int h = task / 192, rem = task % 192, ll = rem / 12, c = rem % 12;
        float a[8] = {};
#pragma unroll
        for (int mm = 0; mm < 16; mm++) {
            const float p = sS[h][ll][mm];
            uint4 vw = *(const uint4*)(sV + mm * ATT_ST + h * DHEAD + c * 8);
            axpy8(a, p, vw);
        }
        ushort4 o0, o1;
        o0.x = f2b(a[0]); o0.y = f2b(a[1]); o0.z = f2b(a[2]); o0.w = f2b(a[3]);
        o1.x = f2b(a[4]); o1.y = f2b(a[5]); o1.z = f2b(a[6]); o1.w = f2b(a[7]);
        u16* dst = qkv + ((long)s * 16 + ll) * QKV_LD + (hh * 4 + h) * DHEAD + c * 8;
        *(ushort4*)dst = o0;
        *(ushort4*)(dst + 4) = o1;
    }
}

// ---------------- MLP GEMM panel (BK=64): part[panel][row] = sum_n relu(ctx@G^T + c)[row,n]*w2[n] ----------------
// XCD-aligned to attn's ctx writes: block bm reads ctx rows for s in [bm*8, bm*8+8),
// which live on XCD (bm>>3)&7 -> map bx so bx&7 == (bm>>3)&7; 3 panels of one bm stay adjacent.
__global__ __launch_bounds__(256) void mlp_gemm(const u16* __restrict__ A, int lda,
                                                const u16* __restrict__ G,
                                                const float* __restrict__ cbias,
                                                const float* __restrict__ w2,
                                                float* __restrict__ part) {
    __shared__ __align__(16) u16 sA[2 * 128 * 32];
    __shared__ __align__(16) u16 sB[2 * 128 * 32];
    __shared__ float rowsum[128];
    const int tid = threadIdx.x;
    const int bx  = blockIdx.x;
    const int xcd = bx & 7;
    const int q   = bx >> 3;       // 0..95
    const int bn  = q % 3;
    const int t   = q / 3;         // 0..31
    const int bm  = ((t >> 3) << 6) | (xcd << 3) | (t & 7);
    if (tid < 128) rowsum[tid] = 0.f;
    const int lane = tid & 63;
    const int wid  = tid >> 6;
    const int wm   = (wid >> 1) * 64;
    const int wn   = (wid & 1) * 64;
    const int ar = tid >> 2;
    const int ac = (tid & 3) * 8;
    const u16* Ap = A + (long)(bm * 128 + ar) * lda + ac;
    const u16* Wp = G + (long)(bn * 128 + ar) * 768 + ac;
    const long a2 = (long)64 * lda;
    const long w2s = (long)64 * 768;
    const int fr = lane & 15;
    const int fq = (lane >> 4) * 8;
    const int rq = (lane >> 4) * 4;

    floatx4 acc[4][4] = {};
    for (int k0 = 0; k0 < 768; k0 += 64) {
#pragma unroll
        for (int h = 0; h < 2; h++) {
            GLDS(Ap + k0 + h * 32,       sA + h * 4096 + tid * 8);
            GLDS(Ap + a2 + k0 + h * 32,  sA + h * 4096 + 2048 + tid * 8);
            GLDS(Wp + k0 + h * 32,       sB + h * 4096 + tid * 8);
            GLDS(Wp + w2s + k0 + h * 32, sB + h * 4096 + 2048 + tid * 8);
        }
        __syncthreads();
#pragma unroll
        for (int h = 0; h < 2; h++) {
            bf16x8 aF[4], bF[4];
#pragma unroll
            for (int i = 0; i < 4; i++) {
                aF[i] = *(const bf16x8*)(sA + h * 4096 + (wm + i * 16 + fr) * 32 + fq);
                bF[i] = *(const bf16x8*)(sB + h * 4096 + (wn + i * 16 + fr) * 32 + fq);
            }
#pragma unroll
            for (int i = 0; i < 4; i++)
#pragma unroll
                for (int j = 0; j < 4; j++)
                    acc[i][j] = __builtin_amdgcn_mfma_f32_16x16x32_bf16(aF[i], bF[j], acc[i][j], 0, 0, 0);
        }
        __syncthreads();
    }
    float partl[4][4] = {};
#pragma unroll
    for (int j = 0; j < 4; j++) {
        const int col = bn * 128 + wn + j * 16 + fr;
        const float cv = cbias[col];
        const float wv = w2[col];
#pragma unroll
        for (int i = 0; i < 4; i++)
#pragma unroll
            for (int r = 0; r < 4; r++)
                partl[i][r] += fmaxf(acc[i][j][r] + cv, 0.f) * wv;
    }
#pragma unroll
    for (int i = 0; i < 4; i++)
#pragma unroll
        for (int r = 0; r < 4; r++) {
            float v = partl[i][r];
#pragma unroll
            for (int off = 8; off > 0; off >>= 1) v += __shfl_xor(v, off);
            if (fr == 0) atomicAdd(&rowsum[wm + i * 16 + rq + r], v);
        }
    __syncthreads();
    if (tid < 128) part[(long)bn * MROWS + bm * 128 + tid] = rowsum[tid];
}

// ---------------- broadcast: block = one s; 16 rows, nontemporal streaming stores ----------------
__global__ __launch_bounds__(256) void bcast_kernel(const float* __restrict__ part,
                                                    const float* __restrict__ b2,
                                                    float* __restrict__ out) {
    const int tid = threadIdx.x;
    const long s  = blockIdx.x;
    const float b2v = b2[0];
#pragma unroll
    for (int l = 0; l < 16; l++) {
        const long p = s * 16 + l;
        const float pv = part[p] + part[MROWS + p] + part[2 * MROWS + p] + b2v;
        floatx4 v4 = {pv, pv, pv, pv};
        floatx4* dst = (floatx4*)(out + ((long)l * S_DIM + s) * S_DIM);
        __builtin_nontemporal_store(v4, dst + tid);
        __builtin_nontemporal_store(v4, dst + tid + 256);
    }
}

extern "C" void kernel_launch(void* const* d_in, const int* in_sizes, int n_in,
                              void* d_out, int out_size, void* d_ws, size_t ws_size,
                              hipStream_t stream) {
    const float* features   = (const float*)d_in[0];
    const float* in_proj_b  = (const float*)d_in[2];
    const float* out_proj_b = (const float*)d_in[4];
    const float* b1 = (const float*)d_in[6];
    const float* w2 = (const float*)d_in[7];
    const float* b2 = (const float*)d_in[8];
    float* out = (float*)d_out;

    char* p = (char*)d_ws;
    u16* fbf = (u16*)p; p += (size_t)MROWS * E_DIM * 2;        // features bf16    50.3 MB
    u16* wib = (u16*)p; p += (size_t)QKV_LD * E_DIM * 2;       // in_proj_w bf16    3.5 MB
    u16* w1b = (u16*)p; p += (size_t)384 * E_DIM * 2;          // w1 bf16           0.6 MB
    u16* WoT = (u16*)p; p += (size_t)E_DIM * E_DIM * 2;        // out_proj_w^T bf16 1.2 MB
    u16* Gbf = (u16*)p; p += (size_t)384 * E_DIM * 2;          // G = W1@Wo bf16    0.6 MB
    float* cbuf  = (float*)p; p += 384 * 4;
    float* partb = (float*)p; p += (size_t)3 * MROWS * 4;      // per-panel row sums 384 KB
    p = (char*)(((size_t)p + 255) & ~(size_t)255);
    u16* qkv = (u16*)p; p += (size_t)MROWS * QKV_LD * 2;       // qkv bf16 (s-major) 151 MB
    u16* ctx = qkv;                                            // attention writes over q cols

    // merged prep (3 cvts + transpose + cbias)
    prep<<<PB4, 256, 0, stream>>>(features, (const float*)d_in[1], (const float*)d_in[5],
                                  (const float*)d_in[3], out_proj_b, b1,
                                  fbf, wib, w1b, WoT, cbuf);
    // merged: G = W1 @ Wo (18 blocks, first) + qkv = features @ in_proj_w^T + b (4608 blocks)
    qkv_g_kernel<<<4626, 256, 0, stream>>>(fbf, E_DIM, wib, in_proj_b, qkv, QKV_LD, E_DIM,
                                           w1b, WoT, Gbf);
    // attention (in place into q-columns), XCD-aligned
    attn_kernel<<<S_DIM * 2, 256, 0, stream>>>(qkv);
    // MLP panels -> partial row sums, XCD-aligned
    mlp_gemm<<<768, 256, 0, stream>>>(ctx, QKV_LD, Gbf, cbuf, w2, partb);
    // broadcast write
    bcast_kernel<<<S_DIM, 256, 0, stream>>>(partb, b2, out);
}